// Round 9
// baseline (278.470 us; speedup 1.0000x reference)
//
#include <hip/hip_runtime.h>
#include <cstdint>

// ---------------- problem constants ----------------
#define BB 8
#define SS 2048
#define DD 1024
#define HH 16
#define HDIM 64
#define MTOT (BB*SS)          // 16384
#define QKVW 2048             // materialized columns: q (1024) + v (1024); k eliminated

typedef __attribute__((ext_vector_type(8))) __bf16 bf16x8;
typedef __attribute__((ext_vector_type(4))) float f32x4;

#define AS1(p) ((const __attribute__((address_space(1))) void*)(p))
#define AS3(p) ((__attribute__((address_space(3))) void*)(p))

__device__ __forceinline__ float bf2f(uint16_t u){
  return __uint_as_float(((uint32_t)u) << 16);
}
__device__ __forceinline__ uint16_t f2bf(float f){
  uint32_t u = __float_as_uint(f);
  return (uint16_t)((u + 0x7fffu + ((u >> 16) & 1u)) >> 16);
}

// ---------------- merged prep kernel ----------------
// [0,2048): x->bf16 ; [2048,6144): W transposes (Wq->Wt0, Wv->Wt1, Wk->Wkt, Wo->WoT);
// [6144,6152]: bias concat(bq,bv)
__global__ __launch_bounds__(256)
void k_prep(const float* __restrict__ x,
            const float* __restrict__ Wq, const float* __restrict__ Wk,
            const float* __restrict__ Wv, const float* __restrict__ Wo,
            const float* __restrict__ bq, const float* __restrict__ bv,
            uint16_t* __restrict__ xb, uint16_t* __restrict__ Wt,
            uint16_t* __restrict__ Wkt, uint16_t* __restrict__ WoT,
            float* __restrict__ bqv)
{
  __shared__ float t[32][33];
  const int blk = blockIdx.x, tid = threadIdx.x;
  if (blk < 2048){
    const int n4 = MTOT*DD/4;
    for (int i = blk*256 + tid; i < n4; i += 2048*256){
      float4 v = reinterpret_cast<const float4*>(x)[i];
      ushort4 o;
      o.x = f2bf(v.x); o.y = f2bf(v.y); o.z = f2bf(v.z); o.w = f2bf(v.w);
      reinterpret_cast<ushort4*>(xb)[i] = o;
    }
  } else if (blk < 6144){
    const int zb = blk - 2048;
    const int z = zb >> 10, rem = zb & 1023;
    const int by = rem >> 5, bx = rem & 31;
    const float* src = (z==0)?Wq:(z==1)?Wv:(z==2)?Wk:Wo;
    uint16_t* dst = (z==0)?Wt:(z==1)?(Wt + 1024*1024):(z==2)?Wkt:WoT;
    const int k0 = by*32, n0 = bx*32;
    const int tx = tid & 31, ty = tid >> 5;
    #pragma unroll
    for (int r = 0; r < 4; ++r)
      t[ty + r*8][tx] = src[(size_t)(k0 + ty + r*8)*1024 + n0 + tx];
    __syncthreads();
    #pragma unroll
    for (int r = 0; r < 4; ++r)
      dst[(size_t)(n0 + ty + r*8)*1024 + k0 + tx] = f2bf(t[tx][ty + r*8]);
  } else {
    const int i = (blk - 6144)*256 + tid;
    if (i < QKVW)
      bqv[i] = (i < 1024) ? bq[i] : bv[i-1024];
  }
}

// ============ 256x256 8-phase GEMM (R6 schedule) + fused alpha-pool epilogue ============
#define BARRIER __builtin_amdgcn_s_barrier()

#define READA(BUF, MH) { \
  const uint16_t* _sl = lds + ((BUF)*4 + (MH))*8192; \
  _Pragma("unroll") \
  for (int f = 0; f < 4; ++f) \
    _Pragma("unroll") \
    for (int ks = 0; ks < 2; ++ks) \
      a[f][ks] = *(const bf16x8*)(_sl + (wm*64 + f*16 + l15)*64 + (((ks*4 + l4) ^ l7)<<3)); \
}

#define READB(BUF, NH, BV) { \
  const uint16_t* _sl = lds + ((BUF)*4 + 2 + (NH))*8192; \
  _Pragma("unroll") \
  for (int j = 0; j < 2; ++j) \
    _Pragma("unroll") \
    for (int ks = 0; ks < 2; ++ks) \
      BV[j][ks] = *(const bf16x8*)(_sl + (wn*32 + j*16 + l15)*64 + (((ks*4 + l4) ^ l7)<<3)); \
}

#define MMA(MH, NH, BV) { \
  __builtin_amdgcn_s_setprio(1); \
  _Pragma("unroll") \
  for (int ks = 0; ks < 2; ++ks) \
    _Pragma("unroll") \
    for (int f = 0; f < 4; ++f) \
      _Pragma("unroll") \
      for (int j = 0; j < 2; ++j) \
        acc[(MH)*4+f][(NH)*2+j] = __builtin_amdgcn_mfma_f32_16x16x32_bf16(a[f][ks], BV[j][ks], acc[(MH)*4+f][(NH)*2+j], 0, 0, 0); \
  __builtin_amdgcn_s_setprio(0); }

#define STAGEA(T, H) { \
  char* _d = (char*)lds + ((((T)&1)*4 + (H))*16384) + wave*1024; \
  _Pragma("unroll") \
  for (int l = 0; l < 2; ++l) \
    __builtin_amdgcn_global_load_lds(AS1(pA + (l*131072 + (H)*65536 + (T)*64)), AS3(_d + l*8192), 16, 0, 0); \
}

#define STAGEB(T, H) { \
  char* _d = (char*)lds + ((((T)&1)*4 + 2 + (H))*16384) + wave*1024; \
  _Pragma("unroll") \
  for (int l = 0; l < 2; ++l) \
    __builtin_amdgcn_global_load_lds(AS1(pB + (l*131072 + (H)*32768 + (T)*64)), AS3(_d + l*8192), 16, 0, 0); \
}

template<int EPI, int NB_T>
__global__ __launch_bounds__(512)
void k_gemm256(const uint16_t* __restrict__ A, const uint16_t* __restrict__ Bt,
               const float* __restrict__ bias, const uint16_t* __restrict__ resid16,
               uint16_t* __restrict__ Cout,
               const float* __restrict__ waP, const float* __restrict__ baP,
               const float* __restrict__ maskP,
               float* __restrict__ cpartA, float* __restrict__ dpartA)
{
  constexpr int N = NB_T * 256;
  __shared__ uint16_t lds[8 * 8192];   // 128 KiB
  const int tid = threadIdx.x;
  const int lane = tid & 63, wave = tid >> 6;
  const int wm = wave >> 2, wn = wave & 3;
  const int l15 = lane & 15, l4 = lane >> 4, l7 = lane & 7;

  const int nwg = gridDim.x, cpx = nwg >> 3, bid = blockIdx.x;
  const int wg = (bid & 7) * cpx + (bid >> 3);
  const int m0 = (wg / NB_T) << 8, n0 = (wg % NB_T) << 8;

  const int colbase = (((tid & 7) ^ ((tid >> 3) & 7)) << 3);
  const uint16_t* pA = A  + (size_t)(m0 + (tid >> 3)) * 1024 + colbase;
  const uint16_t* pB = Bt + (size_t)(n0 + ((tid >> 8) << 6) + ((tid >> 3) & 31)) * 1024 + colbase;

  f32x4 acc[8][4] = {};
  bf16x8 a[4][2], b0[2][2], b1[2][2];

  STAGEA(0,0); STAGEB(0,1); STAGEA(0,1); STAGEB(0,0);
  STAGEA(1,0); STAGEB(1,1); STAGEA(1,1);
  asm volatile("s_waitcnt vmcnt(6)" ::: "memory");
  BARRIER;

  #pragma unroll
  for (int I = 0; I < 7; ++I){
    const int e = 2*I;
    READA(0,0); READB(0,0,b0); STAGEB(e+1, 0);
    BARRIER; MMA(0,0,b0); BARRIER;
    READB(0,1,b1); STAGEA(e+2, 0);
    BARRIER; MMA(0,1,b1); BARRIER;
    READA(0,1); STAGEB(e+2, 1);
    BARRIER; MMA(1,1,b1); BARRIER;
    STAGEA(e+2, 1);
    asm volatile("s_waitcnt vmcnt(6)" ::: "memory");
    BARRIER; MMA(1,0,b0); BARRIER;
    READA(1,0); READB(1,0,b0); STAGEB(e+2, 0);
    BARRIER; MMA(0,0,b0); BARRIER;
    READB(1,1,b1); STAGEA(e+3, 0);
    BARRIER; MMA(0,1,b1); BARRIER;
    READA(1,1); STAGEB(e+3, 1);
    BARRIER; MMA(1,1,b1); BARRIER;
    STAGEA(e+3, 1);
    asm volatile("s_waitcnt vmcnt(6)" ::: "memory");
    BARRIER; MMA(1,0,b0); BARRIER;
  }

  {
    READA(0,0); READB(0,0,b0); STAGEB(15, 0);
    BARRIER; MMA(0,0,b0); BARRIER;
    READB(0,1,b1);
    BARRIER; MMA(0,1,b1); BARRIER;
    READA(0,1);
    BARRIER; MMA(1,1,b1); BARRIER;
    asm volatile("s_waitcnt vmcnt(0)" ::: "memory");
    BARRIER; MMA(1,0,b0); BARRIER;
    READA(1,0); READB(1,0,b0);
    BARRIER; MMA(0,0,b0); BARRIER;
    READB(1,1,b1);
    BARRIER; MMA(0,1,b1); BARRIER;
    READA(1,1);
    BARRIER; MMA(1,1,b1); BARRIER;
    MMA(1,0,b0);
  }

  // ---- C-write
  #pragma unroll
  for (int mh = 0; mh < 2; ++mh)
  #pragma unroll
  for (int f = 0; f < 4; ++f)
  #pragma unroll
  for (int nh = 0; nh < 2; ++nh)
  #pragma unroll
  for (int j = 0; j < 2; ++j){
    const int gcol = n0 + wn*64 + nh*32 + j*16 + l15;
    const float bi = bias[gcol];
    const int rbase = m0 + wm*128 + mh*64 + f*16 + l4*4;
    #pragma unroll
    for (int rr = 0; rr < 4; ++rr){
      const size_t idx = (size_t)(rbase + rr)*N + gcol;
      float v = acc[mh*4+f][nh*2+j][rr] + bi;
      if (EPI == 1) v += bf2f(resid16[idx]);
      Cout[idx] = f2bf(v);
    }
  }

  // ---- fused alpha-pool over q columns (shift-free softmax, exact for small scores)
  if (EPI == 0 && n0 < 1024){
    const int hg = (n0 >> 6) + wn;
    const float bav = baP[0];
    float bcol[2][2], wv[2][2];
    #pragma unroll
    for (int nh = 0; nh < 2; ++nh)
    #pragma unroll
    for (int j = 0; j < 2; ++j){
      const int c = nh*32 + j*16 + l15;
      bcol[nh][j] = bias[n0 + wn*64 + c];
      wv[nh][j]   = waP[c];
    }
    float colacc[2][2] = {{0.f,0.f},{0.f,0.f}};
    float esum = 0.f;
    #pragma unroll
    for (int mh = 0; mh < 2; ++mh)
    #pragma unroll
    for (int f = 0; f < 4; ++f)
    #pragma unroll
    for (int rr = 0; rr < 4; ++rr){
      float qv[2][2];
      float p = 0.f;
      #pragma unroll
      for (int nh = 0; nh < 2; ++nh)
      #pragma unroll
      for (int j = 0; j < 2; ++j){
        qv[nh][j] = acc[mh*4+f][nh*2+j][rr] + bcol[nh][j];
        p += qv[nh][j] * wv[nh][j];
      }
      p += __shfl_xor(p, 1); p += __shfl_xor(p, 2);
      p += __shfl_xor(p, 4); p += __shfl_xor(p, 8);
      const int grow = m0 + wm*128 + mh*64 + f*16 + l4*4 + rr;
      const float E = __expf((p + bav)*0.125f + maskP[grow]);
      esum += E;
      #pragma unroll
      for (int nh = 0; nh < 2; ++nh)
      #pragma unroll
      for (int j = 0; j < 2; ++j)
        colacc[nh][j] += E * qv[nh][j];
    }
    const int rb = (m0 >> 7) + wm;
    #pragma unroll
    for (int nh = 0; nh < 2; ++nh)
    #pragma unroll
    for (int j = 0; j < 2; ++j){
      float v = colacc[nh][j];
      v += __shfl_xor(v, 16); v += __shfl_xor(v, 32);
      if (l4 == 0)
        cpartA[(size_t)rb*1024 + n0 + wn*64 + nh*32 + j*16 + l15] = v;
    }
    esum += __shfl_xor(esum, 16); esum += __shfl_xor(esum, 32);
    if (lane == 0) dpartA[rb*16 + hg] = esum;
  }
}

// ---- mergeA: grid 32 (b x 4 col-chunks), 256 thr -> qavB, wvecB ----
__global__ __launch_bounds__(256)
void k_mergeA(const float* __restrict__ cpartA, const float* __restrict__ dpartA,
              const float* __restrict__ wb,
              float* __restrict__ qavB, float* __restrict__ wvecB)
{
  __shared__ float dsum[16];
  const int blk = blockIdx.x, tid = threadIdx.x;
  const int b = blk >> 2, c = (blk & 3)*256 + tid;
  if (tid < 16){
    float d = 0.f;
    #pragma unroll
    for (int rb = 0; rb < 16; ++rb) d += dpartA[(b*16 + rb)*16 + tid];
    dsum[tid] = d;
  }
  __syncthreads();
  float s = 0.f;
  #pragma unroll
  for (int rb = 0; rb < 16; ++rb) s += cpartA[(size_t)(b*16 + rb)*1024 + c];
  const float qv = s / dsum[(c >> 6) & 15];
  qavB[b*1024 + c]  = qv;
  wvecB[b*1024 + c] = qv * wb[c & 63];
}

// ---- foldB: pB[b,h,k] = sum_d Wk[k, h*64+d]*wvec[b,h,d]; csB = bk.wvec + bb ----
__global__ __launch_bounds__(256)
void k_foldB(const uint16_t* __restrict__ Wkt, const float* __restrict__ wvecB,
             const float* __restrict__ bk, const float* __restrict__ bbP,
             float* __restrict__ pBg, float* __restrict__ csB)
{
  __shared__ float wl[64];
  __shared__ float redc[64];
  const int bh = blockIdx.x, b = bh >> 4, h = bh & 15;
  const int tid = threadIdx.x;
  if (tid < 64) wl[tid] = wvecB[b*1024 + h*64 + tid];
  __syncthreads();
  const int k0 = tid*4;
  float a0 = 0.f, a1 = 0.f, a2 = 0.f, a3 = 0.f;
  for (int d = 0; d < 64; ++d){
    const float w = wl[d];
    const ushort4 r = *(const ushort4*)(Wkt + (size_t)(h*64 + d)*1024 + k0);
    a0 += bf2f(r.x)*w; a1 += bf2f(r.y)*w; a2 += bf2f(r.z)*w; a3 += bf2f(r.w)*w;
  }
  float* dst = pBg + (size_t)bh*1024 + k0;
  dst[0] = a0; dst[1] = a1; dst[2] = a2; dst[3] = a3;
  if (tid < 64) redc[tid] = bk[h*64 + tid] * wl[tid];
  __syncthreads();
  if (tid == 0){
    float s = 0.f;
    for (int i = 0; i < 64; ++i) s += redc[i];
    csB[bh] = s + bbP[0];
  }
}

// ---- scoreB: EB[row][h] = exp((x_row.pB[b,h] + csB)/8 + mask); dpartB per block ----
__global__ __launch_bounds__(256)
void k_scoreB(const uint16_t* __restrict__ xb, const float* __restrict__ pBg,
              const float* __restrict__ csB, const float* __restrict__ mask,
              float* __restrict__ EB, float* __restrict__ dpartB)
{
  __shared__ float csl[16];
  __shared__ float sred[32][4][16];
  __shared__ float EBl[32][16];
  const int blk = blockIdx.x, tid = threadIdx.x;
  const int r0 = blk*32, b = r0 >> 11;
  if (tid < 16) csl[tid] = csB[b*16 + tid];
  const int g = tid >> 4, h = tid & 15, w = tid >> 6;
  // preload this thread's pB slice: head h, cols g*64..g*64+63
  float4 pb[16];
  #pragma unroll
  for (int i = 0; i < 16; ++i)
    pb[i] = *(const float4*)(pBg + (size_t)(b*16 + h)*1024 + g*64 + i*4);
  __syncthreads();
  const uint16_t* xr0 = xb + (size_t)r0*1024 + g*64;
  for (int r = 0; r < 32; ++r){
    const uint16_t* xr = xr0 + (size_t)r*1024;
    float part = 0.f;
    #pragma unroll
    for (int i = 0; i < 8; ++i){
      bf16x8 v = *(const bf16x8*)(xr + i*8);
      part += (float)v[0]*pb[2*i].x   + (float)v[1]*pb[2*i].y
            + (float)v[2]*pb[2*i].z   + (float)v[3]*pb[2*i].w
            + (float)v[4]*pb[2*i+1].x + (float)v[5]*pb[2*i+1].y
            + (float)v[6]*pb[2*i+1].z + (float)v[7]*pb[2*i+1].w;
    }
    part += __shfl_xor(part, 16); part += __shfl_xor(part, 32);
    if ((tid & 48) == 0) sred[r][w][h] = part;
  }
  __syncthreads();
  #pragma unroll
  for (int rr = 0; rr < 2; ++rr){
    const int idx = rr*256 + tid, r = idx >> 4, hh = idx & 15;
    const float s = sred[r][0][hh] + sred[r][1][hh] + sred[r][2][hh] + sred[r][3][hh];
    const float E = __expf((s + csl[hh])*0.125f + mask[r0 + r]);
    EB[(size_t)(r0 + r)*16 + hh] = E;
    EBl[r][hh] = E;
  }
  __syncthreads();
  if (tid < 16){
    float d = 0.f;
    #pragma unroll
    for (int r = 0; r < 32; ++r) d += EBl[r][tid];
    dpartB[blk*16 + tid] = d;
  }
}

// ---- xsumB: xwBp[b,rh,h,col] = sum_rows EB[row][h]*x[row][col] (per row-half) ----
__global__ __launch_bounds__(256)
void k_xsumB(const uint16_t* __restrict__ xb, const float* __restrict__ EB,
             float* __restrict__ xwBp)
{
  __shared__ float part[4][16][64];
  const int blk = blockIdx.x, tid = threadIdx.x;
  const int b = blk >> 5, ch = (blk >> 1) & 15, rh = blk & 1;
  const int col = ch*64 + (tid & 63), rg = tid >> 6;
  float acc[16];
  #pragma unroll
  for (int i = 0; i < 16; ++i) acc[i] = 0.f;
  const int rowbase = b*2048 + rh*1024 + rg*256;
  for (int r = 0; r < 256; ++r){
    const int row = rowbase + r;
    const float xv = bf2f(xb[(size_t)row*1024 + col]);
    const float4* e4 = (const float4*)(EB + (size_t)row*16);
    const float4 e0 = e4[0], e1 = e4[1], e2 = e4[2], e3 = e4[3];
    acc[0] += xv*e0.x; acc[1] += xv*e0.y; acc[2]  += xv*e0.z; acc[3]  += xv*e0.w;
    acc[4] += xv*e1.x; acc[5] += xv*e1.y; acc[6]  += xv*e1.z; acc[7]  += xv*e1.w;
    acc[8] += xv*e2.x; acc[9] += xv*e2.y; acc[10] += xv*e2.z; acc[11] += xv*e2.w;
    acc[12]+= xv*e3.x; acc[13]+= xv*e3.y; acc[14] += xv*e3.z; acc[15] += xv*e3.w;
  }
  #pragma unroll
  for (int hh = 0; hh < 16; ++hh) part[rg][hh][tid & 63] = acc[hh];
  __syncthreads();
  #pragma unroll
  for (int it = 0; it < 4; ++it){
    const int idx = it*256 + tid, hh = idx >> 6, c = idx & 63;
    const float s = part[0][hh][c] + part[1][hh][c] + part[2][hh][c] + part[3][hh][c];
    xwBp[((size_t)(b*2 + rh)*16 + hh)*1024 + ch*64 + c] = s;
  }
}

// ---- finalB: p_av = qav .* ((xwB@Wk_col)/denom + bk); WuPT = diag(p_av)@Wu ----
__global__ __launch_bounds__(256)
void k_finalB(const float* __restrict__ xwBp, const float* __restrict__ dpartB,
              const float* __restrict__ qavB, const uint16_t* __restrict__ Wkt,
              const float* __restrict__ bk, const float* __restrict__ Wu,
              uint16_t* __restrict__ WuPT)
{
  __shared__ float xwl[1024];
  __shared__ float kvl[64];
  __shared__ float pavl[64];
  __shared__ float dsh;
  const int bh = blockIdx.x, b = bh >> 4, h = bh & 15;
  const int tid = threadIdx.x;
  #pragma unroll
  for (int i = 0; i < 4; ++i){
    const int idx = i*256 + tid;
    xwl[idx] = xwBp[((size_t)(b*2 + 0)*16 + h)*1024 + idx]
             + xwBp[((size_t)(b*2 + 1)*16 + h)*1024 + idx];
  }
  if (tid < 64){
    float d = dpartB[(b*64 + tid)*16 + h];
    d += __shfl_xor(d, 1);  d += __shfl_xor(d, 2);  d += __shfl_xor(d, 4);
    d += __shfl_xor(d, 8);  d += __shfl_xor(d, 16); d += __shfl_xor(d, 32);
    if (tid == 0) dsh = d;
  }
  __syncthreads();
  const int d = tid >> 2, q = tid & 3;
  const uint16_t* wrow = Wkt + (size_t)(h*64 + d)*1024 + q*256;
  const float* xwq = xwl + q*256;
  float s = 0.f;
  #pragma unroll
  for (int i = 0; i < 32; ++i){
    bf16x8 v = *(const bf16x8*)(wrow + i*8);
    s += (float)v[0]*xwq[i*8+0] + (float)v[1]*xwq[i*8+1]
       + (float)v[2]*xwq[i*8+2] + (float)v[3]*xwq[i*8+3]
       + (float)v[4]*xwq[i*8+4] + (float)v[5]*xwq[i*8+5]
       + (float)v[6]*xwq[i*8+6] + (float)v[7]*xwq[i*8+7];
  }
  s += __shfl_xor(s, 1); s += __shfl_xor(s, 2);
  if (q == 0) kvl[d] = s;
  __syncthreads();
  if (tid < 64)
    pavl[tid] = qavB[b*1024 + h*64 + tid] * (kvl[tid]/dsh + bk[h*64 + tid]);
  __syncthreads();
  uint16_t* dst = WuPT + (size_t)bh*4096;
  for (int idx = tid; idx < 4096; idx += 256){
    const int i = idx & 63, jcol = idx >> 6;
    dst[idx] = f2bf(pavl[i]*Wu[i*64 + jcol]);
  }
}

// ---------------- newr = v @ WuP + bu + q   (per-head MFMA, qkv width 2048) --------
__global__ __launch_bounds__(256)
void k_newr(const uint16_t* __restrict__ qkv, const uint16_t* __restrict__ WuPT,
            const float* __restrict__ bu, uint16_t* __restrict__ newr)
{
  const int bh = blockIdx.x >> 3, st = blockIdx.x & 7;
  const int b = bh >> 4, h = bh & 15;
  const int tid = threadIdx.x, wave = tid >> 6, lane = tid & 63;
  const int l15 = lane & 15, l4 = lane >> 4;
  const int s0 = st*256 + wave*64;
  const uint16_t* vb = qkv + 1024 + h*64;
  const uint16_t* wt = WuPT + (size_t)bh*4096;

  f32x4 acc[4][4] = {};
  #pragma unroll
  for (int ks = 0; ks < 2; ++ks){
    bf16x8 bfr[4];
    #pragma unroll
    for (int n = 0; n < 4; ++n)
      bfr[n] = *(const bf16x8*)(wt + (n*16 + l15)*64 + ks*32 + l4*8);
    #pragma unroll
    for (int m = 0; m < 4; ++m){
      const int s = s0 + m*16 + l15;
      bf16x8 af = *(const bf16x8*)(vb + (size_t)(b*SS + s)*QKVW + ks*32 + l4*8);
      #pragma unroll
      for (int n = 0; n < 4; ++n)
        acc[m][n] = __builtin_amdgcn_mfma_f32_16x16x32_bf16(af, bfr[n], acc[m][n], 0, 0, 0);
    }
  }
  #pragma unroll
  for (int n = 0; n < 4; ++n){
    const int j = n*16 + l15;
    const float bj = bu[j];
    #pragma unroll
    for (int m = 0; m < 4; ++m){
      #pragma unroll
      for (int r = 0; r < 4; ++r){
        const int s = s0 + m*16 + l4*4 + r;
        const size_t qidx = (size_t)(b*SS + s)*QKVW + h*64 + j;
        const float q = bf2f(qkv[qidx]);
        newr[(size_t)(b*SS + s)*DD + h*64 + j] = f2bf(acc[m][n][r] + bj + q);
      }
    }
  }
}

// ---------------- layernorm (bf16 input h, f32 output) ----------------
__global__ __launch_bounds__(256)
void k_ln(const uint16_t* __restrict__ h16, const float* __restrict__ gamma,
          const float* __restrict__ beta, float* __restrict__ out)
{
  __shared__ float r1[256], r2[256];
  const int row = blockIdx.x, tid = threadIdx.x;
  const ushort4 hv = ((const ushort4*)(h16 + (size_t)row*DD))[tid];
  float v0 = bf2f(hv.x), v1 = bf2f(hv.y), v2 = bf2f(hv.z), v3 = bf2f(hv.w);
  float s  = v0 + v1 + v2 + v3;
  float ss = v0*v0 + v1*v1 + v2*v2 + v3*v3;
  r1[tid] = s; r2[tid] = ss; __syncthreads();
  for (int off = 128; off > 0; off >>= 1){
    if (tid < off){ r1[tid] += r1[tid+off]; r2[tid] += r2[tid+off]; }
    __syncthreads();
  }
  const float mu  = r1[0]*(1.f/1024.f);
  const float var = r2[0]*(1.f/1024.f) - mu*mu;
  const float inv = rsqrtf(var + 1e-6f);
  const float4 g  = ((const float4*)gamma)[tid];
  const float4 be = ((const float4*)beta)[tid];
  float4 o;
  o.x = (v0-mu)*inv*g.x + be.x;
  o.y = (v1-mu)*inv*g.y + be.y;
  o.z = (v2-mu)*inv*g.z + be.z;
  o.w = (v3-mu)*inv*g.w + be.w;
  ((float4*)(out + (size_t)row*DD))[tid] = o;
}

// ---------------- launch ----------------
extern "C" void kernel_launch(void* const* d_in, const int* in_sizes, int n_in,
                              void* d_out, int out_size, void* d_ws, size_t ws_size,
                              hipStream_t stream) {
  const float* x    = (const float*)d_in[0];
  const float* mask = (const float*)d_in[1];
  const float* Wq   = (const float*)d_in[2];
  const float* bq   = (const float*)d_in[3];
  const float* Wk   = (const float*)d_in[4];
  const float* bk   = (const float*)d_in[5];
  const float* Wv   = (const float*)d_in[6];
  const float* bv   = (const float*)d_in[7];
  const float* wa   = (const float*)d_in[8];
  const float* ba   = (const float*)d_in[9];
  const float* wb   = (const float*)d_in[10];
  const float* bb   = (const float*)d_in[11];
  const float* Wu   = (const float*)d_in[12];
  const float* bu   = (const float*)d_in[13];
  const float* Wo   = (const float*)d_in[14];
  const float* bo   = (const float*)d_in[15];
  const float* gamma= (const float*)d_in[16];
  const float* beta = (const float*)d_in[17];
  float* out = (float*)d_out;

  char* ws = (char*)d_ws;
  const size_t MB = 1ull << 20;
  uint16_t* xb    = (uint16_t*)(ws);              // 32 MB [16384][1024] bf16
  uint16_t* Wt    = (uint16_t*)(ws + 32*MB);      // 4 MB  [2048][1024]  bf16 (Wq^T;Wv^T)
  uint16_t* Wkt   = (uint16_t*)(ws + 36*MB);      // 2 MB  [1024][1024]  bf16 (Wk^T)
  uint16_t* WoT   = (uint16_t*)(ws + 38*MB);      // 2 MB  [1024][1024]  bf16
  float*    bqv   = (float*)   (ws + 40*MB);      // 8 KB  concat(bq,bv)
  uint16_t* WuPT  = (uint16_t*)(ws + 41*MB);      // 1 MB  [128][64][64] bf16
  uint16_t* qkv   = (uint16_t*)(ws + 42*MB);      // 64 MB [16384][2048] bf16 (q,v)
  uint16_t* hbuf16= (uint16_t*)(ws + 42*MB);      // 32 MB, aliases dead qkv after newr
  // pooling buffers (live gemm0..finalB; region 110MB+)
  float* cpartA = (float*)(ws + 110*MB);          // 512KB [128][1024]
  float* dpartA = (float*)(ws + 111*MB);          // 8 KB  [128][16]
  float* qavB   = (float*)(ws + 112*MB);          // 32 KB [8][1024]
  float* wvecB  = (float*)(ws + 113*MB);          // 32 KB [8][1024]
  float* pBg    = (float*)(ws + 114*MB);          // 512KB [128][1024]
  float* csB    = (float*)(ws + 115*MB);          // 512 B [128]
  float* EB     = (float*)(ws + 116*MB);          // 1 MB  [16384][16]
  float* dpartB = (float*)(ws + 118*MB);          // 32 KB [512][16]
  float* xwBp   = (float*)(ws + 119*MB);          // 1 MB  [16][16][1024]
  uint16_t* newr= (uint16_t*)(ws + 138*MB);       // 32 MB [16384][1024] bf16

  k_prep<<<6156, 256, 0, stream>>>(x, Wq, Wk, Wv, Wo, bq, bv, xb, Wt, Wkt, WoT, bqv);

  k_gemm256<0,8><<<(MTOT/256)*(QKVW/256), 512, 0, stream>>>(
      xb, Wt, bqv, nullptr, qkv, wa, ba, mask, cpartA, dpartA);

  k_mergeA<<<32, 256, 0, stream>>>(cpartA, dpartA, wb, qavB, wvecB);
  k_foldB<<<128, 256, 0, stream>>>(Wkt, wvecB, bk, bb, pBg, csB);
  k_scoreB<<<512, 256, 0, stream>>>(xb, pBg, csB, mask, EB, dpartB);
  k_xsumB<<<256, 256, 0, stream>>>(xb, EB, xwBp);
  k_finalB<<<128, 256, 0, stream>>>(xwBp, dpartB, qavB, Wkt, bk, Wu, WuPT);

  k_newr<<<BB*HH*8, 256, 0, stream>>>(qkv, WuPT, bu, newr);
  k_gemm256<1,4><<<(MTOT/256)*(DD/256), 512, 0, stream>>>(
      newr, WoT, bo, xb, hbuf16, nullptr, nullptr, nullptr, nullptr, nullptr);
  k_ln<<<MTOT, 256, 0, stream>>>(hbuf16, gamma, beta, out);
}

// Round 10
// 246.476 us; speedup vs baseline: 1.1298x; 1.1298x over previous
//
#include <hip/hip_runtime.h>
#include <cstdint>

// ---------------- problem constants ----------------
#define BB 8
#define SS 2048
#define DD 1024
#define HH 16
#define HDIM 64
#define MTOT (BB*SS)          // 16384
#define QKVW 2048             // materialized columns: q (1024) + v (1024); k eliminated

typedef __attribute__((ext_vector_type(8))) __bf16 bf16x8;
typedef __attribute__((ext_vector_type(4))) float f32x4;

#define AS1(p) ((const __attribute__((address_space(1))) void*)(p))
#define AS3(p) ((__attribute__((address_space(3))) void*)(p))

__device__ __forceinline__ float bf2f(uint16_t u){
  return __uint_as_float(((uint32_t)u) << 16);
}
__device__ __forceinline__ uint16_t f2bf(float f){
  uint32_t u = __float_as_uint(f);
  return (uint16_t)((u + 0x7fffu + ((u >> 16) & 1u)) >> 16);
}

// ---------------- merged prep kernel ----------------
__global__ __launch_bounds__(256)
void k_prep(const float* __restrict__ x,
            const float* __restrict__ Wq, const float* __restrict__ Wk,
            const float* __restrict__ Wv, const float* __restrict__ Wo,
            const float* __restrict__ bq, const float* __restrict__ bv,
            uint16_t* __restrict__ xb, uint16_t* __restrict__ Wt,
            uint16_t* __restrict__ Wkt, uint16_t* __restrict__ WoT,
            float* __restrict__ bqv)
{
  __shared__ float t[32][33];
  const int blk = blockIdx.x, tid = threadIdx.x;
  if (blk < 2048){
    const int n4 = MTOT*DD/4;
    for (int i = blk*256 + tid; i < n4; i += 2048*256){
      float4 v = reinterpret_cast<const float4*>(x)[i];
      ushort4 o;
      o.x = f2bf(v.x); o.y = f2bf(v.y); o.z = f2bf(v.z); o.w = f2bf(v.w);
      reinterpret_cast<ushort4*>(xb)[i] = o;
    }
  } else if (blk < 6144){
    const int zb = blk - 2048;
    const int z = zb >> 10, rem = zb & 1023;
    const int by = rem >> 5, bx = rem & 31;
    const float* src = (z==0)?Wq:(z==1)?Wv:(z==2)?Wk:Wo;
    uint16_t* dst = (z==0)?Wt:(z==1)?(Wt + 1024*1024):(z==2)?Wkt:WoT;
    const int k0 = by*32, n0 = bx*32;
    const int tx = tid & 31, ty = tid >> 5;
    #pragma unroll
    for (int r = 0; r < 4; ++r)
      t[ty + r*8][tx] = src[(size_t)(k0 + ty + r*8)*1024 + n0 + tx];
    __syncthreads();
    #pragma unroll
    for (int r = 0; r < 4; ++r)
      dst[(size_t)(n0 + ty + r*8)*1024 + k0 + tx] = f2bf(t[tx][ty + r*8]);
  } else {
    const int i = (blk - 6144)*256 + tid;
    if (i < QKVW)
      bqv[i] = (i < 1024) ? bq[i] : bv[i-1024];
  }
}

// ============ 256x256 8-phase GEMM (R6 schedule) + fused alpha-pool epilogue ============
#define BARRIER __builtin_amdgcn_s_barrier()

#define READA(BUF, MH) { \
  const uint16_t* _sl = lds + ((BUF)*4 + (MH))*8192; \
  _Pragma("unroll") \
  for (int f = 0; f < 4; ++f) \
    _Pragma("unroll") \
    for (int ks = 0; ks < 2; ++ks) \
      a[f][ks] = *(const bf16x8*)(_sl + (wm*64 + f*16 + l15)*64 + (((ks*4 + l4) ^ l7)<<3)); \
}

#define READB(BUF, NH, BV) { \
  const uint16_t* _sl = lds + ((BUF)*4 + 2 + (NH))*8192; \
  _Pragma("unroll") \
  for (int j = 0; j < 2; ++j) \
    _Pragma("unroll") \
    for (int ks = 0; ks < 2; ++ks) \
      BV[j][ks] = *(const bf16x8*)(_sl + (wn*32 + j*16 + l15)*64 + (((ks*4 + l4) ^ l7)<<3)); \
}

#define MMA(MH, NH, BV) { \
  __builtin_amdgcn_s_setprio(1); \
  _Pragma("unroll") \
  for (int ks = 0; ks < 2; ++ks) \
    _Pragma("unroll") \
    for (int f = 0; f < 4; ++f) \
      _Pragma("unroll") \
      for (int j = 0; j < 2; ++j) \
        acc[(MH)*4+f][(NH)*2+j] = __builtin_amdgcn_mfma_f32_16x16x32_bf16(a[f][ks], BV[j][ks], acc[(MH)*4+f][(NH)*2+j], 0, 0, 0); \
  __builtin_amdgcn_s_setprio(0); }

#define STAGEA(T, H) { \
  char* _d = (char*)lds + ((((T)&1)*4 + (H))*16384) + wave*1024; \
  _Pragma("unroll") \
  for (int l = 0; l < 2; ++l) \
    __builtin_amdgcn_global_load_lds(AS1(pA + (l*131072 + (H)*65536 + (T)*64)), AS3(_d + l*8192), 16, 0, 0); \
}

#define STAGEB(T, H) { \
  char* _d = (char*)lds + ((((T)&1)*4 + 2 + (H))*16384) + wave*1024; \
  _Pragma("unroll") \
  for (int l = 0; l < 2; ++l) \
    __builtin_amdgcn_global_load_lds(AS1(pB + (l*131072 + (H)*32768 + (T)*64)), AS3(_d + l*8192), 16, 0, 0); \
}

template<int EPI, int NB_T>
__global__ __launch_bounds__(512)
void k_gemm256(const uint16_t* __restrict__ A, const uint16_t* __restrict__ Bt,
               const float* __restrict__ bias, const uint16_t* __restrict__ resid16,
               uint16_t* __restrict__ Cout,
               const float* __restrict__ waP, const float* __restrict__ baP,
               const float* __restrict__ maskP,
               float* __restrict__ cpartA, float* __restrict__ dpartA)
{
  constexpr int N = NB_T * 256;
  __shared__ uint16_t lds[8 * 8192];   // 128 KiB
  const int tid = threadIdx.x;
  const int lane = tid & 63, wave = tid >> 6;
  const int wm = wave >> 2, wn = wave & 3;
  const int l15 = lane & 15, l4 = lane >> 4, l7 = lane & 7;

  const int nwg = gridDim.x, cpx = nwg >> 3, bid = blockIdx.x;
  const int wg = (bid & 7) * cpx + (bid >> 3);
  const int m0 = (wg / NB_T) << 8, n0 = (wg % NB_T) << 8;

  const int colbase = (((tid & 7) ^ ((tid >> 3) & 7)) << 3);
  const uint16_t* pA = A  + (size_t)(m0 + (tid >> 3)) * 1024 + colbase;
  const uint16_t* pB = Bt + (size_t)(n0 + ((tid >> 8) << 6) + ((tid >> 3) & 31)) * 1024 + colbase;

  f32x4 acc[8][4] = {};
  bf16x8 a[4][2], b0[2][2], b1[2][2];

  STAGEA(0,0); STAGEB(0,1); STAGEA(0,1); STAGEB(0,0);
  STAGEA(1,0); STAGEB(1,1); STAGEA(1,1);
  asm volatile("s_waitcnt vmcnt(6)" ::: "memory");
  BARRIER;

  #pragma unroll
  for (int I = 0; I < 7; ++I){
    const int e = 2*I;
    READA(0,0); READB(0,0,b0); STAGEB(e+1, 0);
    BARRIER; MMA(0,0,b0); BARRIER;
    READB(0,1,b1); STAGEA(e+2, 0);
    BARRIER; MMA(0,1,b1); BARRIER;
    READA(0,1); STAGEB(e+2, 1);
    BARRIER; MMA(1,1,b1); BARRIER;
    STAGEA(e+2, 1);
    asm volatile("s_waitcnt vmcnt(6)" ::: "memory");
    BARRIER; MMA(1,0,b0); BARRIER;
    READA(1,0); READB(1,0,b0); STAGEB(e+2, 0);
    BARRIER; MMA(0,0,b0); BARRIER;
    READB(1,1,b1); STAGEA(e+3, 0);
    BARRIER; MMA(0,1,b1); BARRIER;
    READA(1,1); STAGEB(e+3, 1);
    BARRIER; MMA(1,1,b1); BARRIER;
    STAGEA(e+3, 1);
    asm volatile("s_waitcnt vmcnt(6)" ::: "memory");
    BARRIER; MMA(1,0,b0); BARRIER;
  }

  {
    READA(0,0); READB(0,0,b0); STAGEB(15, 0);
    BARRIER; MMA(0,0,b0); BARRIER;
    READB(0,1,b1);
    BARRIER; MMA(0,1,b1); BARRIER;
    READA(0,1);
    BARRIER; MMA(1,1,b1); BARRIER;
    asm volatile("s_waitcnt vmcnt(0)" ::: "memory");
    BARRIER; MMA(1,0,b0); BARRIER;
    READA(1,0); READB(1,0,b0);
    BARRIER; MMA(0,0,b0); BARRIER;
    READB(1,1,b1);
    BARRIER; MMA(0,1,b1); BARRIER;
    READA(1,1);
    BARRIER; MMA(1,1,b1); BARRIER;
    MMA(1,0,b0);
  }

  // ---- C-write
  #pragma unroll
  for (int mh = 0; mh < 2; ++mh)
  #pragma unroll
  for (int f = 0; f < 4; ++f)
  #pragma unroll
  for (int nh = 0; nh < 2; ++nh)
  #pragma unroll
  for (int j = 0; j < 2; ++j){
    const int gcol = n0 + wn*64 + nh*32 + j*16 + l15;
    const float bi = bias[gcol];
    const int rbase = m0 + wm*128 + mh*64 + f*16 + l4*4;
    #pragma unroll
    for (int rr = 0; rr < 4; ++rr){
      const size_t idx = (size_t)(rbase + rr)*N + gcol;
      float v = acc[mh*4+f][nh*2+j][rr] + bi;
      if (EPI == 1) v += bf2f(resid16[idx]);
      Cout[idx] = f2bf(v);
    }
  }

  // ---- fused alpha-pool over q columns (shift-free softmax, exact for small scores)
  if (EPI == 0 && n0 < 1024){
    const int hg = (n0 >> 6) + wn;
    const float bav = baP[0];
    float bcol[2][2], wv[2][2];
    #pragma unroll
    for (int nh = 0; nh < 2; ++nh)
    #pragma unroll
    for (int j = 0; j < 2; ++j){
      const int c = nh*32 + j*16 + l15;
      bcol[nh][j] = bias[n0 + wn*64 + c];
      wv[nh][j]   = waP[c];
    }
    float colacc[2][2] = {{0.f,0.f},{0.f,0.f}};
    float esum = 0.f;
    #pragma unroll
    for (int mh = 0; mh < 2; ++mh)
    #pragma unroll
    for (int f = 0; f < 4; ++f)
    #pragma unroll
    for (int rr = 0; rr < 4; ++rr){
      float qv[2][2];
      float p = 0.f;
      #pragma unroll
      for (int nh = 0; nh < 2; ++nh)
      #pragma unroll
      for (int j = 0; j < 2; ++j){
        qv[nh][j] = acc[mh*4+f][nh*2+j][rr] + bcol[nh][j];
        p += qv[nh][j] * wv[nh][j];
      }
      p += __shfl_xor(p, 1); p += __shfl_xor(p, 2);
      p += __shfl_xor(p, 4); p += __shfl_xor(p, 8);
      const int grow = m0 + wm*128 + mh*64 + f*16 + l4*4 + rr;
      const float E = __expf((p + bav)*0.125f + maskP[grow]);
      esum += E;
      #pragma unroll
      for (int nh = 0; nh < 2; ++nh)
      #pragma unroll
      for (int j = 0; j < 2; ++j)
        colacc[nh][j] += E * qv[nh][j];
    }
    const int rb = (m0 >> 7) + wm;
    #pragma unroll
    for (int nh = 0; nh < 2; ++nh)
    #pragma unroll
    for (int j = 0; j < 2; ++j){
      float v = colacc[nh][j];
      v += __shfl_xor(v, 16); v += __shfl_xor(v, 32);
      if (l4 == 0)
        cpartA[(size_t)rb*1024 + n0 + wn*64 + nh*32 + j*16 + l15] = v;
    }
    esum += __shfl_xor(esum, 16); esum += __shfl_xor(esum, 32);
    if (lane == 0) dpartA[rb*16 + hg] = esum;
  }
}

// ---- mergeA: grid 32 (b x 4 col-chunks), 256 thr -> qavB, wvecB ----
__global__ __launch_bounds__(256)
void k_mergeA(const float* __restrict__ cpartA, const float* __restrict__ dpartA,
              const float* __restrict__ wb,
              float* __restrict__ qavB, float* __restrict__ wvecB)
{
  __shared__ float dsum[16];
  const int blk = blockIdx.x, tid = threadIdx.x;
  const int b = blk >> 2, c = (blk & 3)*256 + tid;
  if (tid < 16){
    float d = 0.f;
    #pragma unroll
    for (int rb = 0; rb < 16; ++rb) d += dpartA[(b*16 + rb)*16 + tid];
    dsum[tid] = d;
  }
  __syncthreads();
  float s = 0.f;
  #pragma unroll
  for (int rb = 0; rb < 16; ++rb) s += cpartA[(size_t)(b*16 + rb)*1024 + c];
  const float qv = s / dsum[(c >> 6) & 15];
  qavB[b*1024 + c]  = qv;
  wvecB[b*1024 + c] = qv * wb[c & 63];
}

// ---- foldB: pB[b,h,k] = sum_d Wk[k, h*64+d]*wvec[b,h,d]; csB = bk.wvec + bb ----
__global__ __launch_bounds__(256)
void k_foldB(const uint16_t* __restrict__ Wkt, const float* __restrict__ wvecB,
             const float* __restrict__ bk, const float* __restrict__ bbP,
             float* __restrict__ pBg, float* __restrict__ csB)
{
  __shared__ float wl[64];
  __shared__ float redc[64];
  const int bh = blockIdx.x, b = bh >> 4, h = bh & 15;
  const int tid = threadIdx.x;
  if (tid < 64) wl[tid] = wvecB[b*1024 + h*64 + tid];
  __syncthreads();
  const int k0 = tid*4;
  float a0 = 0.f, a1 = 0.f, a2 = 0.f, a3 = 0.f;
  for (int d = 0; d < 64; ++d){
    const float w = wl[d];
    const ushort4 r = *(const ushort4*)(Wkt + (size_t)(h*64 + d)*1024 + k0);
    a0 += bf2f(r.x)*w; a1 += bf2f(r.y)*w; a2 += bf2f(r.z)*w; a3 += bf2f(r.w)*w;
  }
  float* dst = pBg + (size_t)bh*1024 + k0;
  dst[0] = a0; dst[1] = a1; dst[2] = a2; dst[3] = a3;
  if (tid < 64) redc[tid] = bk[h*64 + tid] * wl[tid];
  __syncthreads();
  if (tid == 0){
    float s = 0.f;
    for (int i = 0; i < 64; ++i) s += redc[i];
    csB[bh] = s + bbP[0];
  }
}

// ---- scoreB2: grid 1024 (b x 128 rowchunks of 16 rows), 256 thr = 16 h x 16 cg ----
// EB[row][h] = exp((x_row.pB[b,h] + csB)/8 + mask[row]); dpartB[blk][h] = sum E.
__global__ __launch_bounds__(256)
void k_scoreB2(const uint16_t* __restrict__ xb, const float* __restrict__ pBg,
               const float* __restrict__ csB, const float* __restrict__ mask,
               float* __restrict__ EB, float* __restrict__ dpartB)
{
  __shared__ float sred[16][16][4];   // [row][h][wave]
  __shared__ float el[16][16];        // [row][h]
  __shared__ float csl[16];
  const int blk = blockIdx.x, tid = threadIdx.x;
  const int b = blk >> 7, rc = blk & 127;
  const int r0 = b*2048 + rc*16;      // global row base (mask-flat too)
  const int h = tid & 15, cg = tid >> 4;   // cg in [0,16): 64-col group
  const int lane = tid & 63, w = tid >> 6;
  if (tid < 16) csl[tid] = csB[b*16 + tid];

  // probe: 64 f32 for (h, cols cg*64..cg*64+63)
  float pr[64];
  const float4* pb4 = (const float4*)(pBg + (size_t)(b*16 + h)*1024 + cg*64);
  #pragma unroll
  for (int i = 0; i < 16; ++i){
    const float4 t = pb4[i];
    pr[4*i] = t.x; pr[4*i+1] = t.y; pr[4*i+2] = t.z; pr[4*i+3] = t.w;
  }
  const uint16_t* xr = xb + (size_t)r0*1024 + cg*64;
  for (int r = 0; r < 16; ++r){
    const bf16x8* row8 = (const bf16x8*)(xr + (size_t)r*1024);
    float s = 0.f;
    #pragma unroll
    for (int i = 0; i < 8; ++i){
      const bf16x8 v = row8[i];
      #pragma unroll
      for (int e = 0; e < 8; ++e) s += (float)v[e] * pr[i*8 + e];
    }
    // reduce over in-wave col-groups (lane bits 4,5 = cg&3)
    s += __shfl_xor(s, 16); s += __shfl_xor(s, 32);
    if ((lane >> 4) == 0) sred[r][h][w] = s;
  }
  __syncthreads();
  {
    const int r = tid >> 4, h2 = tid & 15;
    const float s = sred[r][h2][0] + sred[r][h2][1] + sred[r][h2][2] + sred[r][h2][3];
    const float E = __expf((s + csl[h2])*0.125f + mask[r0 + r]);
    EB[(size_t)(r0 + r)*16 + h2] = E;
    el[r][h2] = E;
  }
  __syncthreads();
  if (tid < 16){
    float d = 0.f;
    #pragma unroll
    for (int r = 0; r < 16; ++r) d += el[r][tid];
    dpartB[blk*16 + tid] = d;
  }
}

// ---- xsumB2: grid 1024 (b x 16 rowchunks(128) x 8 colslices(128)), 256 thr ----
// xwp[b][rc][h][col] = sum_{rows in chunk} EB[row][h]*x[row][col]
__global__ __launch_bounds__(256)
void k_xsumB2(const uint16_t* __restrict__ xb, const float* __restrict__ EB,
              float* __restrict__ xwp)
{
  __shared__ float part[4][16][128];   // [rg][h][col]  32 KB
  const int blk = blockIdx.x, tid = threadIdx.x;
  const int b = blk >> 7, rem = blk & 127;
  const int rc = rem >> 3, cs = rem & 7;
  const int c2 = tid & 63, rg = tid >> 6;
  const int col0 = cs*128 + c2*2;
  const int row0 = b*2048 + rc*128 + rg*32;

  float acc0[16], acc1[16];
  #pragma unroll
  for (int i = 0; i < 16; ++i){ acc0[i] = 0.f; acc1[i] = 0.f; }

  for (int r = 0; r < 32; ++r){
    const int row = row0 + r;
    const uint32_t xv = *(const uint32_t*)(xb + (size_t)row*1024 + col0);
    const float x0 = __uint_as_float(xv << 16);
    const float x1 = __uint_as_float(xv & 0xffff0000u);
    const float4* e4 = (const float4*)(EB + (size_t)row*16);
    const float4 e0 = e4[0], e1 = e4[1], e2 = e4[2], e3 = e4[3];
    acc0[0] += x0*e0.x; acc1[0] += x1*e0.x;
    acc0[1] += x0*e0.y; acc1[1] += x1*e0.y;
    acc0[2] += x0*e0.z; acc1[2] += x1*e0.z;
    acc0[3] += x0*e0.w; acc1[3] += x1*e0.w;
    acc0[4] += x0*e1.x; acc1[4] += x1*e1.x;
    acc0[5] += x0*e1.y; acc1[5] += x1*e1.y;
    acc0[6] += x0*e1.z; acc1[6] += x1*e1.z;
    acc0[7] += x0*e1.w; acc1[7] += x1*e1.w;
    acc0[8] += x0*e2.x; acc1[8] += x1*e2.x;
    acc0[9] += x0*e2.y; acc1[9] += x1*e2.y;
    acc0[10] += x0*e2.z; acc1[10] += x1*e2.z;
    acc0[11] += x0*e2.w; acc1[11] += x1*e2.w;
    acc0[12] += x0*e3.x; acc1[12] += x1*e3.x;
    acc0[13] += x0*e3.y; acc1[13] += x1*e3.y;
    acc0[14] += x0*e3.z; acc1[14] += x1*e3.z;
    acc0[15] += x0*e3.w; acc1[15] += x1*e3.w;
  }
  #pragma unroll
  for (int hh = 0; hh < 16; ++hh){
    part[rg][hh][c2*2]     = acc0[hh];
    part[rg][hh][c2*2 + 1] = acc1[hh];
  }
  __syncthreads();
  #pragma unroll
  for (int it = 0; it < 8; ++it){
    const int idx = it*256 + tid;
    const int hh = idx >> 7, c = idx & 127;
    const float s = part[0][hh][c] + part[1][hh][c] + part[2][hh][c] + part[3][hh][c];
    xwp[((size_t)(b*16 + rc)*16 + hh)*1024 + cs*128 + c] = s;
  }
}

// ---- finalB: p_av = qav .* ((xwB@Wk_col)/denom + bk); WuPT = diag(p_av)@Wu ----
__global__ __launch_bounds__(256)
void k_finalB(const float* __restrict__ xwp, const float* __restrict__ dpartB,
              const float* __restrict__ qavB, const uint16_t* __restrict__ Wkt,
              const float* __restrict__ bk, const float* __restrict__ Wu,
              uint16_t* __restrict__ WuPT)
{
  __shared__ float xwl[1024];
  __shared__ float kvl[64];
  __shared__ float pavl[64];
  __shared__ float dsh;
  const int bh = blockIdx.x, b = bh >> 4, h = bh & 15;
  const int tid = threadIdx.x;
  #pragma unroll
  for (int i = 0; i < 4; ++i){
    const int idx = i*256 + tid;
    float s = 0.f;
    #pragma unroll
    for (int rc = 0; rc < 16; ++rc)
      s += xwp[((size_t)(b*16 + rc)*16 + h)*1024 + idx];
    xwl[idx] = s;
  }
  if (tid < 64){
    float d = dpartB[(b*128 + tid)*16 + h] + dpartB[(b*128 + 64 + tid)*16 + h];
    d += __shfl_xor(d, 1);  d += __shfl_xor(d, 2);  d += __shfl_xor(d, 4);
    d += __shfl_xor(d, 8);  d += __shfl_xor(d, 16); d += __shfl_xor(d, 32);
    if (tid == 0) dsh = d;
  }
  __syncthreads();
  const int d = tid >> 2, q = tid & 3;
  const uint16_t* wrow = Wkt + (size_t)(h*64 + d)*1024 + q*256;
  const float* xwq = xwl + q*256;
  float s = 0.f;
  #pragma unroll
  for (int i = 0; i < 32; ++i){
    bf16x8 v = *(const bf16x8*)(wrow + i*8);
    s += (float)v[0]*xwq[i*8+0] + (float)v[1]*xwq[i*8+1]
       + (float)v[2]*xwq[i*8+2] + (float)v[3]*xwq[i*8+3]
       + (float)v[4]*xwq[i*8+4] + (float)v[5]*xwq[i*8+5]
       + (float)v[6]*xwq[i*8+6] + (float)v[7]*xwq[i*8+7];
  }
  s += __shfl_xor(s, 1); s += __shfl_xor(s, 2);
  if (q == 0) kvl[d] = s;
  __syncthreads();
  if (tid < 64)
    pavl[tid] = qavB[b*1024 + h*64 + tid] * (kvl[tid]/dsh + bk[h*64 + tid]);
  __syncthreads();
  uint16_t* dst = WuPT + (size_t)bh*4096;
  for (int idx = tid; idx < 4096; idx += 256){
    const int i = idx & 63, jcol = idx >> 6;
    dst[idx] = f2bf(pavl[i]*Wu[i*64 + jcol]);
  }
}

// ---------------- newr = v @ WuP + bu + q   (per-head MFMA, qkv width 2048) --------
__global__ __launch_bounds__(256)
void k_newr(const uint16_t* __restrict__ qkv, const uint16_t* __restrict__ WuPT,
            const float* __restrict__ bu, uint16_t* __restrict__ newr)
{
  const int bh = blockIdx.x >> 3, st = blockIdx.x & 7;
  const int b = bh >> 4, h = bh & 15;
  const int tid = threadIdx.x, wave = tid >> 6, lane = tid & 63;
  const int l15 = lane & 15, l4 = lane >> 4;
  const int s0 = st*256 + wave*64;
  const uint16_t* vb = qkv + 1024 + h*64;
  const uint16_t* wt = WuPT + (size_t)bh*4096;

  f32x4 acc[4][4] = {};
  #pragma unroll
  for (int ks = 0; ks < 2; ++ks){
    bf16x8 bfr[4];
    #pragma unroll
    for (int n = 0; n < 4; ++n)
      bfr[n] = *(const bf16x8*)(wt + (n*16 + l15)*64 + ks*32 + l4*8);
    #pragma unroll
    for (int m = 0; m < 4; ++m){
      const int s = s0 + m*16 + l15;
      bf16x8 af = *(const bf16x8*)(vb + (size_t)(b*SS + s)*QKVW + ks*32 + l4*8);
      #pragma unroll
      for (int n = 0; n < 4; ++n)
        acc[m][n] = __builtin_amdgcn_mfma_f32_16x16x32_bf16(af, bfr[n], acc[m][n], 0, 0, 0);
    }
  }
  #pragma unroll
  for (int n = 0; n < 4; ++n){
    const int j = n*16 + l15;
    const float bj = bu[j];
    #pragma unroll
    for (int m = 0; m < 4; ++m){
      #pragma unroll
      for (int r = 0; r < 4; ++r){
        const int s = s0 + m*16 + l4*4 + r;
        const size_t qidx = (size_t)(b*SS + s)*QKVW + h*64 + j;
        const float q = bf2f(qkv[qidx]);
        newr[(size_t)(b*SS + s)*DD + h*64 + j] = f2bf(acc[m][n][r] + bj + q);
      }
    }
  }
}

// ---------------- layernorm (bf16 input h, f32 output) ----------------
__global__ __launch_bounds__(256)
void k_ln(const uint16_t* __restrict__ h16, const float* __restrict__ gamma,
          const float* __restrict__ beta, float* __restrict__ out)
{
  __shared__ float r1[256], r2[256];
  const int row = blockIdx.x, tid = threadIdx.x;
  const ushort4 hv = ((const ushort4*)(h16 + (size_t)row*DD))[tid];
  float v0 = bf2f(hv.x), v1 = bf2f(hv.y), v2 = bf2f(hv.z), v3 = bf2f(hv.w);
  float s  = v0 + v1 + v2 + v3;
  float ss = v0*v0 + v1*v1 + v2*v2 + v3*v3;
  r1[tid] = s; r2[tid] = ss; __syncthreads();
  for (int off = 128; off > 0; off >>= 1){
    if (tid < off){ r1[tid] += r1[tid+off]; r2[tid] += r2[tid+off]; }
    __syncthreads();
  }
  const float mu  = r1[0]*(1.f/1024.f);
  const float var = r2[0]*(1.f/1024.f) - mu*mu;
  const float inv = rsqrtf(var + 1e-6f);
  const float4 g  = ((const float4*)gamma)[tid];
  const float4 be = ((const float4*)beta)[tid];
  float4 o;
  o.x = (v0-mu)*inv*g.x + be.x;
  o.y = (v1-mu)*inv*g.y + be.y;
  o.z = (v2-mu)*inv*g.z + be.z;
  o.w = (v3-mu)*inv*g.w + be.w;
  ((float4*)(out + (size_t)row*DD))[tid] = o;
}

// ---------------- launch ----------------
extern "C" void kernel_launch(void* const* d_in, const int* in_sizes, int n_in,
                              void* d_out, int out_size, void* d_ws, size_t ws_size,
                              hipStream_t stream) {
  const float* x    = (const float*)d_in[0];
  const float* mask = (const float*)d_in[1];
  const float* Wq   = (const float*)d_in[2];
  const float* bq   = (const float*)d_in[3];
  const float* Wk   = (const float*)d_in[4];
  const float* bk   = (const float*)d_in[5];
  const float* Wv   = (const float*)d_in[6];
  const float* bv   = (const float*)d_in[7];
  const float* wa   = (const float*)d_in[8];
  const float* ba   = (const float*)d_in[9];
  const float* wb   = (const float*)d_in[10];
  const float* bb   = (const float*)d_in[11];
  const float* Wu   = (const float*)d_in[12];
  const float* bu   = (const float*)d_in[13];
  const float* Wo   = (const float*)d_in[14];
  const float* bo   = (const float*)d_in[15];
  const float* gamma= (const float*)d_in[16];
  const float* beta = (const float*)d_in[17];
  float* out = (float*)d_out;

  char* ws = (char*)d_ws;
  const size_t MB = 1ull << 20;
  uint16_t* xb    = (uint16_t*)(ws);              // 32 MB [16384][1024] bf16
  uint16_t* Wt    = (uint16_t*)(ws + 32*MB);      // 4 MB  [2048][1024]  bf16 (Wq^T;Wv^T)
  uint16_t* Wkt   = (uint16_t*)(ws + 36*MB);      // 2 MB  [1024][1024]  bf16 (Wk^T)
  uint16_t* WoT   = (uint16_t*)(ws + 38*MB);      // 2 MB  [1024][1024]  bf16
  float*    bqv   = (float*)   (ws + 40*MB);      // 8 KB  concat(bq,bv)
  uint16_t* WuPT  = (uint16_t*)(ws + 41*MB);      // 1 MB  [128][64][64] bf16
  uint16_t* qkv   = (uint16_t*)(ws + 42*MB);      // 64 MB [16384][2048] bf16 (q,v)
  uint16_t* hbuf16= (uint16_t*)(ws + 42*MB);      // 32 MB, aliases dead qkv after newr
  float* cpartA = (float*)(ws + 110*MB);          // 512KB [128][1024]
  float* dpartA = (float*)(ws + 111*MB);          // 8 KB  [128][16]
  float* qavB   = (float*)(ws + 112*MB);          // 32 KB [8][1024]
  float* wvecB  = (float*)(ws + 113*MB);          // 32 KB [8][1024]
  float* pBg    = (float*)(ws + 114*MB);          // 512KB [128][1024]
  float* csB    = (float*)(ws + 115*MB);          // 512 B [128]
  float* EB     = (float*)(ws + 116*MB);          // 1 MB  [16384][16]
  float* dpartB = (float*)(ws + 118*MB);          // 64 KB [1024][16]
  float* xwp    = (float*)(ws + 119*MB);          // 8 MB  [8][16][16][1024]
  uint16_t* newr= (uint16_t*)(ws + 138*MB);       // 32 MB [16384][1024] bf16

  k_prep<<<6156, 256, 0, stream>>>(x, Wq, Wk, Wv, Wo, bq, bv, xb, Wt, Wkt, WoT, bqv);

  k_gemm256<0,8><<<(MTOT/256)*(QKVW/256), 512, 0, stream>>>(
      xb, Wt, bqv, nullptr, qkv, wa, ba, mask, cpartA, dpartA);

  k_mergeA<<<32, 256, 0, stream>>>(cpartA, dpartA, wb, qavB, wvecB);
  k_foldB<<<128, 256, 0, stream>>>(Wkt, wvecB, bk, bb, pBg, csB);
  k_scoreB2<<<1024, 256, 0, stream>>>(xb, pBg, csB, mask, EB, dpartB);
  k_xsumB2<<<1024, 256, 0, stream>>>(xb, EB, xwp);
  k_finalB<<<128, 256, 0, stream>>>(xwp, dpartB, qavB, Wkt, bk, Wu, WuPT);

  k_newr<<<BB*HH*8, 256, 0, stream>>>(qkv, WuPT, bu, newr);
  k_gemm256<1,4><<<(MTOT/256)*(DD/256), 512, 0, stream>>>(
      newr, WoT, bo, xb, hbuf16, nullptr, nullptr, nullptr, nullptr, nullptr);
  k_ln<<<MTOT, 256, 0, stream>>>(hbuf16, gamma, beta, out);
}

// Round 11
// 235.562 us; speedup vs baseline: 1.1822x; 1.0463x over previous
//
#include <hip/hip_runtime.h>
#include <cstdint>

// ---------------- problem constants ----------------
#define BB 8
#define SS 2048
#define DD 1024
#define HH 16
#define HDIM 64
#define MTOT (BB*SS)          // 16384
#define QKVW 2048             // materialized columns: q (1024) + v (1024); k eliminated

typedef __attribute__((ext_vector_type(8))) __bf16 bf16x8;
typedef __attribute__((ext_vector_type(4))) float f32x4;

#define AS1(p) ((const __attribute__((address_space(1))) void*)(p))
#define AS3(p) ((__attribute__((address_space(3))) void*)(p))

__device__ __forceinline__ float bf2f(uint16_t u){
  return __uint_as_float(((uint32_t)u) << 16);
}
__device__ __forceinline__ uint16_t f2bf(float f){
  uint32_t u = __float_as_uint(f);
  return (uint16_t)((u + 0x7fffu + ((u >> 16) & 1u)) >> 16);
}

// ---------------- merged prep kernel ----------------
__global__ __launch_bounds__(256)
void k_prep(const float* __restrict__ x,
            const float* __restrict__ Wq, const float* __restrict__ Wk,
            const float* __restrict__ Wv, const float* __restrict__ Wo,
            const float* __restrict__ bq, const float* __restrict__ bv,
            uint16_t* __restrict__ xb, uint16_t* __restrict__ Wt,
            uint16_t* __restrict__ Wkt, uint16_t* __restrict__ WoT,
            float* __restrict__ bqv)
{
  __shared__ float t[32][33];
  const int blk = blockIdx.x, tid = threadIdx.x;
  if (blk < 2048){
    const int n4 = MTOT*DD/4;
    for (int i = blk*256 + tid; i < n4; i += 2048*256){
      float4 v = reinterpret_cast<const float4*>(x)[i];
      ushort4 o;
      o.x = f2bf(v.x); o.y = f2bf(v.y); o.z = f2bf(v.z); o.w = f2bf(v.w);
      reinterpret_cast<ushort4*>(xb)[i] = o;
    }
  } else if (blk < 6144){
    const int zb = blk - 2048;
    const int z = zb >> 10, rem = zb & 1023;
    const int by = rem >> 5, bx = rem & 31;
    const float* src = (z==0)?Wq:(z==1)?Wv:(z==2)?Wk:Wo;
    uint16_t* dst = (z==0)?Wt:(z==1)?(Wt + 1024*1024):(z==2)?Wkt:WoT;
    const int k0 = by*32, n0 = bx*32;
    const int tx = tid & 31, ty = tid >> 5;
    #pragma unroll
    for (int r = 0; r < 4; ++r)
      t[ty + r*8][tx] = src[(size_t)(k0 + ty + r*8)*1024 + n0 + tx];
    __syncthreads();
    #pragma unroll
    for (int r = 0; r < 4; ++r)
      dst[(size_t)(n0 + ty + r*8)*1024 + k0 + tx] = f2bf(t[tx][ty + r*8]);
  } else {
    const int i = (blk - 6144)*256 + tid;
    if (i < QKVW)
      bqv[i] = (i < 1024) ? bq[i] : bv[i-1024];
  }
}

// ============ 256x256 8-phase GEMM (R6 schedule) + fused alpha-pool epilogue ============
#define BARRIER __builtin_amdgcn_s_barrier()

#define READA(BUF, MH) { \
  const uint16_t* _sl = lds + ((BUF)*4 + (MH))*8192; \
  _Pragma("unroll") \
  for (int f = 0; f < 4; ++f) \
    _Pragma("unroll") \
    for (int ks = 0; ks < 2; ++ks) \
      a[f][ks] = *(const bf16x8*)(_sl + (wm*64 + f*16 + l15)*64 + (((ks*4 + l4) ^ l7)<<3)); \
}

#define READB(BUF, NH, BV) { \
  const uint16_t* _sl = lds + ((BUF)*4 + 2 + (NH))*8192; \
  _Pragma("unroll") \
  for (int j = 0; j < 2; ++j) \
    _Pragma("unroll") \
    for (int ks = 0; ks < 2; ++ks) \
      BV[j][ks] = *(const bf16x8*)(_sl + (wn*32 + j*16 + l15)*64 + (((ks*4 + l4) ^ l7)<<3)); \
}

#define MMA(MH, NH, BV) { \
  __builtin_amdgcn_s_setprio(1); \
  _Pragma("unroll") \
  for (int ks = 0; ks < 2; ++ks) \
    _Pragma("unroll") \
    for (int f = 0; f < 4; ++f) \
      _Pragma("unroll") \
      for (int j = 0; j < 2; ++j) \
        acc[(MH)*4+f][(NH)*2+j] = __builtin_amdgcn_mfma_f32_16x16x32_bf16(a[f][ks], BV[j][ks], acc[(MH)*4+f][(NH)*2+j], 0, 0, 0); \
  __builtin_amdgcn_s_setprio(0); }

#define STAGEA(T, H) { \
  char* _d = (char*)lds + ((((T)&1)*4 + (H))*16384) + wave*1024; \
  _Pragma("unroll") \
  for (int l = 0; l < 2; ++l) \
    __builtin_amdgcn_global_load_lds(AS1(pA + (l*131072 + (H)*65536 + (T)*64)), AS3(_d + l*8192), 16, 0, 0); \
}

#define STAGEB(T, H) { \
  char* _d = (char*)lds + ((((T)&1)*4 + 2 + (H))*16384) + wave*1024; \
  _Pragma("unroll") \
  for (int l = 0; l < 2; ++l) \
    __builtin_amdgcn_global_load_lds(AS1(pB + (l*131072 + (H)*32768 + (T)*64)), AS3(_d + l*8192), 16, 0, 0); \
}

template<int EPI, int NB_T>
__global__ __launch_bounds__(512)
void k_gemm256(const uint16_t* __restrict__ A, const uint16_t* __restrict__ Bt,
               const float* __restrict__ bias, const uint16_t* __restrict__ resid16,
               uint16_t* __restrict__ Cout,
               const float* __restrict__ waP, const float* __restrict__ baP,
               const float* __restrict__ maskP,
               float* __restrict__ cpartA, float* __restrict__ dpartA)
{
  constexpr int N = NB_T * 256;
  __shared__ uint16_t lds[8 * 8192];   // 128 KiB
  const int tid = threadIdx.x;
  const int lane = tid & 63, wave = tid >> 6;
  const int wm = wave >> 2, wn = wave & 3;
  const int l15 = lane & 15, l4 = lane >> 4, l7 = lane & 7;

  const int nwg = gridDim.x, cpx = nwg >> 3, bid = blockIdx.x;
  const int wg = (bid & 7) * cpx + (bid >> 3);
  const int m0 = (wg / NB_T) << 8, n0 = (wg % NB_T) << 8;

  const int colbase = (((tid & 7) ^ ((tid >> 3) & 7)) << 3);
  const uint16_t* pA = A  + (size_t)(m0 + (tid >> 3)) * 1024 + colbase;
  const uint16_t* pB = Bt + (size_t)(n0 + ((tid >> 8) << 6) + ((tid >> 3) & 31)) * 1024 + colbase;

  f32x4 acc[8][4] = {};
  bf16x8 a[4][2], b0[2][2], b1[2][2];

  STAGEA(0,0); STAGEB(0,1); STAGEA(0,1); STAGEB(0,0);
  STAGEA(1,0); STAGEB(1,1); STAGEA(1,1);
  asm volatile("s_waitcnt vmcnt(6)" ::: "memory");
  BARRIER;

  #pragma unroll
  for (int I = 0; I < 7; ++I){
    const int e = 2*I;
    READA(0,0); READB(0,0,b0); STAGEB(e+1, 0);
    BARRIER; MMA(0,0,b0); BARRIER;
    READB(0,1,b1); STAGEA(e+2, 0);
    BARRIER; MMA(0,1,b1); BARRIER;
    READA(0,1); STAGEB(e+2, 1);
    BARRIER; MMA(1,1,b1); BARRIER;
    STAGEA(e+2, 1);
    asm volatile("s_waitcnt vmcnt(6)" ::: "memory");
    BARRIER; MMA(1,0,b0); BARRIER;
    READA(1,0); READB(1,0,b0); STAGEB(e+2, 0);
    BARRIER; MMA(0,0,b0); BARRIER;
    READB(1,1,b1); STAGEA(e+3, 0);
    BARRIER; MMA(0,1,b1); BARRIER;
    READA(1,1); STAGEB(e+3, 1);
    BARRIER; MMA(1,1,b1); BARRIER;
    STAGEA(e+3, 1);
    asm volatile("s_waitcnt vmcnt(6)" ::: "memory");
    BARRIER; MMA(1,0,b0); BARRIER;
  }

  {
    READA(0,0); READB(0,0,b0); STAGEB(15, 0);
    BARRIER; MMA(0,0,b0); BARRIER;
    READB(0,1,b1);
    BARRIER; MMA(0,1,b1); BARRIER;
    READA(0,1);
    BARRIER; MMA(1,1,b1); BARRIER;
    asm volatile("s_waitcnt vmcnt(0)" ::: "memory");
    BARRIER; MMA(1,0,b0); BARRIER;
    READA(1,0); READB(1,0,b0);
    BARRIER; MMA(0,0,b0); BARRIER;
    READB(1,1,b1);
    BARRIER; MMA(0,1,b1); BARRIER;
    READA(1,1);
    BARRIER; MMA(1,1,b1); BARRIER;
    MMA(1,0,b0);
  }

  // ---- C-write
  #pragma unroll
  for (int mh = 0; mh < 2; ++mh)
  #pragma unroll
  for (int f = 0; f < 4; ++f)
  #pragma unroll
  for (int nh = 0; nh < 2; ++nh)
  #pragma unroll
  for (int j = 0; j < 2; ++j){
    const int gcol = n0 + wn*64 + nh*32 + j*16 + l15;
    const float bi = bias[gcol];
    const int rbase = m0 + wm*128 + mh*64 + f*16 + l4*4;
    #pragma unroll
    for (int rr = 0; rr < 4; ++rr){
      const size_t idx = (size_t)(rbase + rr)*N + gcol;
      float v = acc[mh*4+f][nh*2+j][rr] + bi;
      if (EPI == 1) v += bf2f(resid16[idx]);
      Cout[idx] = f2bf(v);
    }
  }

  // ---- fused alpha-pool over q columns (shift-free softmax, exact for small scores)
  if (EPI == 0 && n0 < 1024){
    const int hg = (n0 >> 6) + wn;
    const float bav = baP[0];
    float bcol[2][2], wv[2][2];
    #pragma unroll
    for (int nh = 0; nh < 2; ++nh)
    #pragma unroll
    for (int j = 0; j < 2; ++j){
      const int c = nh*32 + j*16 + l15;
      bcol[nh][j] = bias[n0 + wn*64 + c];
      wv[nh][j]   = waP[c];
    }
    float colacc[2][2] = {{0.f,0.f},{0.f,0.f}};
    float esum = 0.f;
    #pragma unroll
    for (int mh = 0; mh < 2; ++mh)
    #pragma unroll
    for (int f = 0; f < 4; ++f)
    #pragma unroll
    for (int rr = 0; rr < 4; ++rr){
      float qv[2][2];
      float p = 0.f;
      #pragma unroll
      for (int nh = 0; nh < 2; ++nh)
      #pragma unroll
      for (int j = 0; j < 2; ++j){
        qv[nh][j] = acc[mh*4+f][nh*2+j][rr] + bcol[nh][j];
        p += qv[nh][j] * wv[nh][j];
      }
      p += __shfl_xor(p, 1); p += __shfl_xor(p, 2);
      p += __shfl_xor(p, 4); p += __shfl_xor(p, 8);
      const int grow = m0 + wm*128 + mh*64 + f*16 + l4*4 + rr;
      const float E = __expf((p + bav)*0.125f + maskP[grow]);
      esum += E;
      #pragma unroll
      for (int nh = 0; nh < 2; ++nh)
      #pragma unroll
      for (int j = 0; j < 2; ++j)
        colacc[nh][j] += E * qv[nh][j];
    }
    const int rb = (m0 >> 7) + wm;
    #pragma unroll
    for (int nh = 0; nh < 2; ++nh)
    #pragma unroll
    for (int j = 0; j < 2; ++j){
      float v = colacc[nh][j];
      v += __shfl_xor(v, 16); v += __shfl_xor(v, 32);
      if (l4 == 0)
        cpartA[(size_t)rb*1024 + n0 + wn*64 + nh*32 + j*16 + l15] = v;
    }
    esum += __shfl_xor(esum, 16); esum += __shfl_xor(esum, 32);
    if (lane == 0) dpartA[rb*16 + hg] = esum;
  }
}

// ---- mergeA: grid 32 (b x 4 col-chunks), 256 thr -> qavB, wvecB ----
__global__ __launch_bounds__(256)
void k_mergeA(const float* __restrict__ cpartA, const float* __restrict__ dpartA,
              const float* __restrict__ wb,
              float* __restrict__ qavB, float* __restrict__ wvecB)
{
  __shared__ float dsum[16];
  const int blk = blockIdx.x, tid = threadIdx.x;
  const int b = blk >> 2, c = (blk & 3)*256 + tid;
  if (tid < 16){
    float d = 0.f;
    #pragma unroll
    for (int rb = 0; rb < 16; ++rb) d += dpartA[(b*16 + rb)*16 + tid];
    dsum[tid] = d;
  }
  __syncthreads();
  float s = 0.f;
  #pragma unroll
  for (int rb = 0; rb < 16; ++rb) s += cpartA[(size_t)(b*16 + rb)*1024 + c];
  const float qv = s / dsum[(c >> 6) & 15];
  qavB[b*1024 + c]  = qv;
  wvecB[b*1024 + c] = qv * wb[c & 63];
}

// ---- foldB: pB[b,h,k] = sum_d Wk[k, h*64+d]*wvec[b,h,d]; csB = bk.wvec + bb ----
__global__ __launch_bounds__(256)
void k_foldB(const uint16_t* __restrict__ Wkt, const float* __restrict__ wvecB,
             const float* __restrict__ bk, const float* __restrict__ bbP,
             float* __restrict__ pBg, float* __restrict__ csB)
{
  __shared__ float wl[64];
  __shared__ float redc[64];
  const int bh = blockIdx.x, b = bh >> 4, h = bh & 15;
  const int tid = threadIdx.x;
  if (tid < 64) wl[tid] = wvecB[b*1024 + h*64 + tid];
  __syncthreads();
  const int k0 = tid*4;
  float a0 = 0.f, a1 = 0.f, a2 = 0.f, a3 = 0.f;
  for (int d = 0; d < 64; ++d){
    const float w = wl[d];
    const ushort4 r = *(const ushort4*)(Wkt + (size_t)(h*64 + d)*1024 + k0);
    a0 += bf2f(r.x)*w; a1 += bf2f(r.y)*w; a2 += bf2f(r.z)*w; a3 += bf2f(r.w)*w;
  }
  float* dst = pBg + (size_t)bh*1024 + k0;
  dst[0] = a0; dst[1] = a1; dst[2] = a2; dst[3] = a3;
  if (tid < 64) redc[tid] = bk[h*64 + tid] * wl[tid];
  __syncthreads();
  if (tid == 0){
    float s = 0.f;
    for (int i = 0; i < 64; ++i) s += redc[i];
    csB[bh] = s + bbP[0];
  }
}

// ---- poolX: FUSED beta score + weighted x-sum. grid 256 (64 rows each), 512 thr ----
// thread = (h = tid>>5, cs = tid&31) owns head h, cols cs*32..cs*32+31.
// Per row: load 32 x cols (shared between score-dot and accumulation),
// butterfly-reduce the 32 cs-lanes for the full 1024-dot, E = exp(...),
// acc[i] += E*x. Writes per-block partials xwp[blk][h][1024] and dpartB[blk][h].
__global__ __launch_bounds__(512)
void k_poolX(const uint16_t* __restrict__ xb, const float* __restrict__ pBg,
             const float* __restrict__ csB, const float* __restrict__ mask,
             float* __restrict__ xwp, float* __restrict__ dpartB)
{
  const int blk = blockIdx.x, tid = threadIdx.x;
  const int b = blk >> 5;
  const int h = tid >> 5, cs = tid & 31;
  const int col0 = cs*32;

  float pr[32];
  {
    const float4* p4 = (const float4*)(pBg + (size_t)(b*16 + h)*1024 + col0);
    #pragma unroll
    for (int i = 0; i < 8; ++i){
      const float4 t = p4[i];
      pr[4*i] = t.x; pr[4*i+1] = t.y; pr[4*i+2] = t.z; pr[4*i+3] = t.w;
    }
  }
  const float csh = csB[b*16 + h];
  float acc[32];
  #pragma unroll
  for (int i = 0; i < 32; ++i) acc[i] = 0.f;
  float esum = 0.f;

  const int row0 = blk*64;
  for (int r = 0; r < 64; ++r){
    const int row = row0 + r;
    const uint16_t* xr = xb + (size_t)row*1024 + col0;
    float xv[32];
    #pragma unroll
    for (int i = 0; i < 4; ++i){
      const bf16x8 v = *(const bf16x8*)(xr + i*8);
      #pragma unroll
      for (int e = 0; e < 8; ++e) xv[i*8+e] = (float)v[e];
    }
    float s = 0.f;
    #pragma unroll
    for (int i = 0; i < 32; ++i) s += xv[i]*pr[i];
    s += __shfl_xor(s, 1); s += __shfl_xor(s, 2); s += __shfl_xor(s, 4);
    s += __shfl_xor(s, 8); s += __shfl_xor(s, 16);
    const float E = __expf((s + csh)*0.125f + mask[row]);
    esum += E;
    #pragma unroll
    for (int i = 0; i < 32; ++i) acc[i] += E*xv[i];
  }
  float* dst = xwp + (size_t)(blk*16 + h)*1024 + col0;
  #pragma unroll
  for (int i = 0; i < 8; ++i)
    ((float4*)dst)[i] = (float4){acc[4*i], acc[4*i+1], acc[4*i+2], acc[4*i+3]};
  if (cs == 0) dpartB[blk*16 + h] = esum;
}

// ---- finalB: p_av = qav .* ((xwB@Wk_col)/denom + bk); WuPT = diag(p_av)@Wu ----
__global__ __launch_bounds__(512)
void k_finalB(const float* __restrict__ xwp, const float* __restrict__ dpartB,
              const float* __restrict__ qavB, const uint16_t* __restrict__ Wkt,
              const float* __restrict__ bk, const float* __restrict__ Wu,
              uint16_t* __restrict__ WuPT)
{
  __shared__ float xwl[1024];
  __shared__ float kvl[64];
  __shared__ float pavl[64];
  __shared__ float dsh;
  const int bh = blockIdx.x, b = bh >> 4, h = bh & 15;
  const int tid = threadIdx.x;
  #pragma unroll
  for (int i = 0; i < 2; ++i){
    const int idx = i*512 + tid;
    float s = 0.f;
    #pragma unroll
    for (int rc = 0; rc < 32; ++rc)
      s += xwp[((size_t)(b*32 + rc)*16 + h)*1024 + idx];
    xwl[idx] = s;
  }
  if (tid < 32){
    float d = dpartB[(b*32 + tid)*16 + h];
    d += __shfl_xor(d, 1); d += __shfl_xor(d, 2); d += __shfl_xor(d, 4);
    d += __shfl_xor(d, 8); d += __shfl_xor(d, 16);
    if (tid == 0) dsh = d;
  }
  __syncthreads();
  const int d = tid >> 3, q = tid & 7;
  const uint16_t* wrow = Wkt + (size_t)(h*64 + d)*1024 + q*128;
  const float* xwq = xwl + q*128;
  float s = 0.f;
  #pragma unroll
  for (int i = 0; i < 16; ++i){
    const bf16x8 v = *(const bf16x8*)(wrow + i*8);
    #pragma unroll
    for (int e = 0; e < 8; ++e) s += (float)v[e]*xwq[i*8+e];
  }
  s += __shfl_xor(s, 1); s += __shfl_xor(s, 2); s += __shfl_xor(s, 4);
  if (q == 0) kvl[d] = s;
  __syncthreads();
  if (tid < 64)
    pavl[tid] = qavB[b*1024 + h*64 + tid] * (kvl[tid]/dsh + bk[h*64 + tid]);
  __syncthreads();
  uint16_t* dst = WuPT + (size_t)bh*4096;
  for (int idx = tid; idx < 4096; idx += 512){
    const int i = idx & 63, jcol = idx >> 6;
    dst[idx] = f2bf(pavl[i]*Wu[i*64 + jcol]);
  }
}

// ---------------- newr = v @ WuP + bu + q   (per-head MFMA, qkv width 2048) --------
__global__ __launch_bounds__(256)
void k_newr(const uint16_t* __restrict__ qkv, const uint16_t* __restrict__ WuPT,
            const float* __restrict__ bu, uint16_t* __restrict__ newr)
{
  const int bh = blockIdx.x >> 3, st = blockIdx.x & 7;
  const int b = bh >> 4, h = bh & 15;
  const int tid = threadIdx.x, wave = tid >> 6, lane = tid & 63;
  const int l15 = lane & 15, l4 = lane >> 4;
  const int s0 = st*256 + wave*64;
  const uint16_t* vb = qkv + 1024 + h*64;
  const uint16_t* wt = WuPT + (size_t)bh*4096;

  f32x4 acc[4][4] = {};
  #pragma unroll
  for (int ks = 0; ks < 2; ++ks){
    bf16x8 bfr[4];
    #pragma unroll
    for (int n = 0; n < 4; ++n)
      bfr[n] = *(const bf16x8*)(wt + (n*16 + l15)*64 + ks*32 + l4*8);
    #pragma unroll
    for (int m = 0; m < 4; ++m){
      const int s = s0 + m*16 + l15;
      bf16x8 af = *(const bf16x8*)(vb + (size_t)(b*SS + s)*QKVW + ks*32 + l4*8);
      #pragma unroll
      for (int n = 0; n < 4; ++n)
        acc[m][n] = __builtin_amdgcn_mfma_f32_16x16x32_bf16(af, bfr[n], acc[m][n], 0, 0, 0);
    }
  }
  #pragma unroll
  for (int n = 0; n < 4; ++n){
    const int j = n*16 + l15;
    const float bj = bu[j];
    #pragma unroll
    for (int m = 0; m < 4; ++m){
      #pragma unroll
      for (int r = 0; r < 4; ++r){
        const int s = s0 + m*16 + l4*4 + r;
        const size_t qidx = (size_t)(b*SS + s)*QKVW + h*64 + j;
        const float q = bf2f(qkv[qidx]);
        newr[(size_t)(b*SS + s)*DD + h*64 + j] = f2bf(acc[m][n][r] + bj + q);
      }
    }
  }
}

// ---------------- layernorm (bf16 input h, f32 output) ----------------
__global__ __launch_bounds__(256)
void k_ln(const uint16_t* __restrict__ h16, const float* __restrict__ gamma,
          const float* __restrict__ beta, float* __restrict__ out)
{
  __shared__ float r1[256], r2[256];
  const int row = blockIdx.x, tid = threadIdx.x;
  const ushort4 hv = ((const ushort4*)(h16 + (size_t)row*DD))[tid];
  float v0 = bf2f(hv.x), v1 = bf2f(hv.y), v2 = bf2f(hv.z), v3 = bf2f(hv.w);
  float s  = v0 + v1 + v2 + v3;
  float ss = v0*v0 + v1*v1 + v2*v2 + v3*v3;
  r1[tid] = s; r2[tid] = ss; __syncthreads();
  for (int off = 128; off > 0; off >>= 1){
    if (tid < off){ r1[tid] += r1[tid+off]; r2[tid] += r2[tid+off]; }
    __syncthreads();
  }
  const float mu  = r1[0]*(1.f/1024.f);
  const float var = r2[0]*(1.f/1024.f) - mu*mu;
  const float inv = rsqrtf(var + 1e-6f);
  const float4 g  = ((const float4*)gamma)[tid];
  const float4 be = ((const float4*)beta)[tid];
  float4 o;
  o.x = (v0-mu)*inv*g.x + be.x;
  o.y = (v1-mu)*inv*g.y + be.y;
  o.z = (v2-mu)*inv*g.z + be.z;
  o.w = (v3-mu)*inv*g.w + be.w;
  ((float4*)(out + (size_t)row*DD))[tid] = o;
}

// ---------------- launch ----------------
extern "C" void kernel_launch(void* const* d_in, const int* in_sizes, int n_in,
                              void* d_out, int out_size, void* d_ws, size_t ws_size,
                              hipStream_t stream) {
  const float* x    = (const float*)d_in[0];
  const float* mask = (const float*)d_in[1];
  const float* Wq   = (const float*)d_in[2];
  const float* bq   = (const float*)d_in[3];
  const float* Wk   = (const float*)d_in[4];
  const float* bk   = (const float*)d_in[5];
  const float* Wv   = (const float*)d_in[6];
  const float* bv   = (const float*)d_in[7];
  const float* wa   = (const float*)d_in[8];
  const float* ba   = (const float*)d_in[9];
  const float* wb   = (const float*)d_in[10];
  const float* bb   = (const float*)d_in[11];
  const float* Wu   = (const float*)d_in[12];
  const float* bu   = (const float*)d_in[13];
  const float* Wo   = (const float*)d_in[14];
  const float* bo   = (const float*)d_in[15];
  const float* gamma= (const float*)d_in[16];
  const float* beta = (const float*)d_in[17];
  float* out = (float*)d_out;

  char* ws = (char*)d_ws;
  const size_t MB = 1ull << 20;
  uint16_t* xb    = (uint16_t*)(ws);              // 32 MB [16384][1024] bf16
  uint16_t* Wt    = (uint16_t*)(ws + 32*MB);      // 4 MB  [2048][1024]  bf16 (Wq^T;Wv^T)
  uint16_t* Wkt   = (uint16_t*)(ws + 36*MB);      // 2 MB  [1024][1024]  bf16 (Wk^T)
  uint16_t* WoT   = (uint16_t*)(ws + 38*MB);      // 2 MB  [1024][1024]  bf16
  float*    bqv   = (float*)   (ws + 40*MB);      // 8 KB  concat(bq,bv)
  uint16_t* WuPT  = (uint16_t*)(ws + 41*MB);      // 1 MB  [128][64][64] bf16
  uint16_t* qkv   = (uint16_t*)(ws + 42*MB);      // 64 MB [16384][2048] bf16 (q,v)
  uint16_t* hbuf16= (uint16_t*)(ws + 42*MB);      // 32 MB, aliases dead qkv after newr
  float* cpartA = (float*)(ws + 110*MB);          // 512KB [128][1024]
  float* dpartA = (float*)(ws + 111*MB);          // 8 KB  [128][16]
  float* qavB   = (float*)(ws + 112*MB);          // 32 KB [8][1024]
  float* wvecB  = (float*)(ws + 113*MB);          // 32 KB [8][1024]
  float* pBg    = (float*)(ws + 114*MB);          // 512KB [128][1024]
  float* csB    = (float*)(ws + 115*MB);          // 512 B [128]
  float* dpartB = (float*)(ws + 116*MB);          // 16 KB [256][16]
  float* xwp    = (float*)(ws + 117*MB);          // 16 MB [256][16][1024]
  uint16_t* newr= (uint16_t*)(ws + 138*MB);       // 32 MB [16384][1024] bf16

  k_prep<<<6156, 256, 0, stream>>>(x, Wq, Wk, Wv, Wo, bq, bv, xb, Wt, Wkt, WoT, bqv);

  k_gemm256<0,8><<<(MTOT/256)*(QKVW/256), 512, 0, stream>>>(
      xb, Wt, bqv, nullptr, qkv, wa, ba, mask, cpartA, dpartA);

  k_mergeA<<<32, 256, 0, stream>>>(cpartA, dpartA, wb, qavB, wvecB);
  k_foldB<<<128, 256, 0, stream>>>(Wkt, wvecB, bk, bb, pBg, csB);
  k_poolX<<<256, 512, 0, stream>>>(xb, pBg, csB, mask, xwp, dpartB);
  k_finalB<<<128, 512, 0, stream>>>(xwp, dpartB, qavB, Wkt, bk, Wu, WuPT);

  k_newr<<<BB*HH*8, 256, 0, stream>>>(qkv, WuPT, bu, newr);
  k_gemm256<1,4><<<(MTOT/256)*(DD/256), 512, 0, stream>>>(
      newr, WoT, bo, xb, hbuf16, nullptr, nullptr, nullptr, nullptr, nullptr);
  k_ln<<<MTOT, 256, 0, stream>>>(hbuf16, gamma, beta, out);
}

// Round 12
// 221.249 us; speedup vs baseline: 1.2586x; 1.0647x over previous
//
#include <hip/hip_runtime.h>
#include <cstdint>

// ---------------- problem constants ----------------
#define BB 8
#define SS 2048
#define DD 1024
#define HH 16
#define HDIM 64
#define MTOT (BB*SS)          // 16384
#define QKVW 2048             // materialized columns: q (1024) + v (1024); k eliminated

typedef __attribute__((ext_vector_type(8))) __bf16 bf16x8;
typedef __attribute__((ext_vector_type(4))) float f32x4;

#define AS1(p) ((const __attribute__((address_space(1))) void*)(p))
#define AS3(p) ((__attribute__((address_space(3))) void*)(p))

__device__ __forceinline__ float bf2f(uint16_t u){
  return __uint_as_float(((uint32_t)u) << 16);
}
__device__ __forceinline__ uint16_t f2bf(float f){
  uint32_t u = __float_as_uint(f);
  return (uint16_t)((u + 0x7fffu + ((u >> 16) & 1u)) >> 16);
}

// ---------------- merged prep kernel ----------------
__global__ __launch_bounds__(256)
void k_prep(const float* __restrict__ x,
            const float* __restrict__ Wq, const float* __restrict__ Wk,
            const float* __restrict__ Wv, const float* __restrict__ Wo,
            const float* __restrict__ bq, const float* __restrict__ bv,
            uint16_t* __restrict__ xb, uint16_t* __restrict__ Wt,
            uint16_t* __restrict__ Wkt, uint16_t* __restrict__ WoT,
            float* __restrict__ bqv)
{
  __shared__ float t[32][33];
  const int blk = blockIdx.x, tid = threadIdx.x;
  if (blk < 2048){
    const int n4 = MTOT*DD/4;
    for (int i = blk*256 + tid; i < n4; i += 2048*256){
      float4 v = reinterpret_cast<const float4*>(x)[i];
      ushort4 o;
      o.x = f2bf(v.x); o.y = f2bf(v.y); o.z = f2bf(v.z); o.w = f2bf(v.w);
      reinterpret_cast<ushort4*>(xb)[i] = o;
    }
  } else if (blk < 6144){
    const int zb = blk - 2048;
    const int z = zb >> 10, rem = zb & 1023;
    const int by = rem >> 5, bx = rem & 31;
    const float* src = (z==0)?Wq:(z==1)?Wv:(z==2)?Wk:Wo;
    uint16_t* dst = (z==0)?Wt:(z==1)?(Wt + 1024*1024):(z==2)?Wkt:WoT;
    const int k0 = by*32, n0 = bx*32;
    const int tx = tid & 31, ty = tid >> 5;
    #pragma unroll
    for (int r = 0; r < 4; ++r)
      t[ty + r*8][tx] = src[(size_t)(k0 + ty + r*8)*1024 + n0 + tx];
    __syncthreads();
    #pragma unroll
    for (int r = 0; r < 4; ++r)
      dst[(size_t)(n0 + ty + r*8)*1024 + k0 + tx] = f2bf(t[tx][ty + r*8]);
  } else {
    const int i = (blk - 6144)*256 + tid;
    if (i < QKVW)
      bqv[i] = (i < 1024) ? bq[i] : bv[i-1024];
  }
}

// ============ 256x256 8-phase GEMM (R6 schedule) + fused alpha-pool epilogue ============
#define BARRIER __builtin_amdgcn_s_barrier()

#define READA(BUF, MH) { \
  const uint16_t* _sl = lds + ((BUF)*4 + (MH))*8192; \
  _Pragma("unroll") \
  for (int f = 0; f < 4; ++f) \
    _Pragma("unroll") \
    for (int ks = 0; ks < 2; ++ks) \
      a[f][ks] = *(const bf16x8*)(_sl + (wm*64 + f*16 + l15)*64 + (((ks*4 + l4) ^ l7)<<3)); \
}

#define READB(BUF, NH, BV) { \
  const uint16_t* _sl = lds + ((BUF)*4 + 2 + (NH))*8192; \
  _Pragma("unroll") \
  for (int j = 0; j < 2; ++j) \
    _Pragma("unroll") \
    for (int ks = 0; ks < 2; ++ks) \
      BV[j][ks] = *(const bf16x8*)(_sl + (wn*32 + j*16 + l15)*64 + (((ks*4 + l4) ^ l7)<<3)); \
}

#define MMA(MH, NH, BV) { \
  __builtin_amdgcn_s_setprio(1); \
  _Pragma("unroll") \
  for (int ks = 0; ks < 2; ++ks) \
    _Pragma("unroll") \
    for (int f = 0; f < 4; ++f) \
      _Pragma("unroll") \
      for (int j = 0; j < 2; ++j) \
        acc[(MH)*4+f][(NH)*2+j] = __builtin_amdgcn_mfma_f32_16x16x32_bf16(a[f][ks], BV[j][ks], acc[(MH)*4+f][(NH)*2+j], 0, 0, 0); \
  __builtin_amdgcn_s_setprio(0); }

#define STAGEA(T, H) { \
  char* _d = (char*)lds + ((((T)&1)*4 + (H))*16384) + wave*1024; \
  _Pragma("unroll") \
  for (int l = 0; l < 2; ++l) \
    __builtin_amdgcn_global_load_lds(AS1(pA + (l*131072 + (H)*65536 + (T)*64)), AS3(_d + l*8192), 16, 0, 0); \
}

#define STAGEB(T, H) { \
  char* _d = (char*)lds + ((((T)&1)*4 + 2 + (H))*16384) + wave*1024; \
  _Pragma("unroll") \
  for (int l = 0; l < 2; ++l) \
    __builtin_amdgcn_global_load_lds(AS1(pB + (l*131072 + (H)*32768 + (T)*64)), AS3(_d + l*8192), 16, 0, 0); \
}

template<int EPI, int NB_T>
__global__ __launch_bounds__(512)
void k_gemm256(const uint16_t* __restrict__ A, const uint16_t* __restrict__ Bt,
               const float* __restrict__ bias, const uint16_t* __restrict__ resid16,
               uint16_t* __restrict__ Cout,
               const float* __restrict__ waP, const float* __restrict__ baP,
               const float* __restrict__ maskP,
               float* __restrict__ cpartA, float* __restrict__ dpartA)
{
  constexpr int N = NB_T * 256;
  __shared__ uint16_t lds[8 * 8192];   // 128 KiB
  const int tid = threadIdx.x;
  const int lane = tid & 63, wave = tid >> 6;
  const int wm = wave >> 2, wn = wave & 3;
  const int l15 = lane & 15, l4 = lane >> 4, l7 = lane & 7;

  const int nwg = gridDim.x, cpx = nwg >> 3, bid = blockIdx.x;
  const int wg = (bid & 7) * cpx + (bid >> 3);
  const int m0 = (wg / NB_T) << 8, n0 = (wg % NB_T) << 8;

  const int colbase = (((tid & 7) ^ ((tid >> 3) & 7)) << 3);
  const uint16_t* pA = A  + (size_t)(m0 + (tid >> 3)) * 1024 + colbase;
  const uint16_t* pB = Bt + (size_t)(n0 + ((tid >> 8) << 6) + ((tid >> 3) & 31)) * 1024 + colbase;

  f32x4 acc[8][4] = {};
  bf16x8 a[4][2], b0[2][2], b1[2][2];

  STAGEA(0,0); STAGEB(0,1); STAGEA(0,1); STAGEB(0,0);
  STAGEA(1,0); STAGEB(1,1); STAGEA(1,1);
  asm volatile("s_waitcnt vmcnt(6)" ::: "memory");
  BARRIER;

  #pragma unroll
  for (int I = 0; I < 7; ++I){
    const int e = 2*I;
    READA(0,0); READB(0,0,b0); STAGEB(e+1, 0);
    BARRIER; MMA(0,0,b0); BARRIER;
    READB(0,1,b1); STAGEA(e+2, 0);
    BARRIER; MMA(0,1,b1); BARRIER;
    READA(0,1); STAGEB(e+2, 1);
    BARRIER; MMA(1,1,b1); BARRIER;
    STAGEA(e+2, 1);
    asm volatile("s_waitcnt vmcnt(6)" ::: "memory");
    BARRIER; MMA(1,0,b0); BARRIER;
    READA(1,0); READB(1,0,b0); STAGEB(e+2, 0);
    BARRIER; MMA(0,0,b0); BARRIER;
    READB(1,1,b1); STAGEA(e+3, 0);
    BARRIER; MMA(0,1,b1); BARRIER;
    READA(1,1); STAGEB(e+3, 1);
    BARRIER; MMA(1,1,b1); BARRIER;
    STAGEA(e+3, 1);
    asm volatile("s_waitcnt vmcnt(6)" ::: "memory");
    BARRIER; MMA(1,0,b0); BARRIER;
  }

  {
    READA(0,0); READB(0,0,b0); STAGEB(15, 0);
    BARRIER; MMA(0,0,b0); BARRIER;
    READB(0,1,b1);
    BARRIER; MMA(0,1,b1); BARRIER;
    READA(0,1);
    BARRIER; MMA(1,1,b1); BARRIER;
    asm volatile("s_waitcnt vmcnt(0)" ::: "memory");
    BARRIER; MMA(1,0,b0); BARRIER;
    READA(1,0); READB(1,0,b0);
    BARRIER; MMA(0,0,b0); BARRIER;
    READB(1,1,b1);
    BARRIER; MMA(0,1,b1); BARRIER;
    READA(1,1);
    BARRIER; MMA(1,1,b1); BARRIER;
    MMA(1,0,b0);
  }

  // ---- C-write
  #pragma unroll
  for (int mh = 0; mh < 2; ++mh)
  #pragma unroll
  for (int f = 0; f < 4; ++f)
  #pragma unroll
  for (int nh = 0; nh < 2; ++nh)
  #pragma unroll
  for (int j = 0; j < 2; ++j){
    const int gcol = n0 + wn*64 + nh*32 + j*16 + l15;
    const float bi = bias[gcol];
    const int rbase = m0 + wm*128 + mh*64 + f*16 + l4*4;
    #pragma unroll
    for (int rr = 0; rr < 4; ++rr){
      const size_t idx = (size_t)(rbase + rr)*N + gcol;
      float v = acc[mh*4+f][nh*2+j][rr] + bi;
      if (EPI == 1) v += bf2f(resid16[idx]);
      Cout[idx] = f2bf(v);
    }
  }

  // ---- fused alpha-pool over q columns (shift-free softmax, exact for small scores)
  if (EPI == 0 && n0 < 1024){
    const int hg = (n0 >> 6) + wn;
    const float bav = baP[0];
    float bcol[2][2], wv[2][2];
    #pragma unroll
    for (int nh = 0; nh < 2; ++nh)
    #pragma unroll
    for (int j = 0; j < 2; ++j){
      const int c = nh*32 + j*16 + l15;
      bcol[nh][j] = bias[n0 + wn*64 + c];
      wv[nh][j]   = waP[c];
    }
    float colacc[2][2] = {{0.f,0.f},{0.f,0.f}};
    float esum = 0.f;
    #pragma unroll
    for (int mh = 0; mh < 2; ++mh)
    #pragma unroll
    for (int f = 0; f < 4; ++f)
    #pragma unroll
    for (int rr = 0; rr < 4; ++rr){
      float qv[2][2];
      float p = 0.f;
      #pragma unroll
      for (int nh = 0; nh < 2; ++nh)
      #pragma unroll
      for (int j = 0; j < 2; ++j){
        qv[nh][j] = acc[mh*4+f][nh*2+j][rr] + bcol[nh][j];
        p += qv[nh][j] * wv[nh][j];
      }
      p += __shfl_xor(p, 1); p += __shfl_xor(p, 2);
      p += __shfl_xor(p, 4); p += __shfl_xor(p, 8);
      const int grow = m0 + wm*128 + mh*64 + f*16 + l4*4 + rr;
      const float E = __expf((p + bav)*0.125f + maskP[grow]);
      esum += E;
      #pragma unroll
      for (int nh = 0; nh < 2; ++nh)
      #pragma unroll
      for (int j = 0; j < 2; ++j)
        colacc[nh][j] += E * qv[nh][j];
    }
    const int rb = (m0 >> 7) + wm;
    #pragma unroll
    for (int nh = 0; nh < 2; ++nh)
    #pragma unroll
    for (int j = 0; j < 2; ++j){
      float v = colacc[nh][j];
      v += __shfl_xor(v, 16); v += __shfl_xor(v, 32);
      if (l4 == 0)
        cpartA[(size_t)rb*1024 + n0 + wn*64 + nh*32 + j*16 + l15] = v;
    }
    esum += __shfl_xor(esum, 16); esum += __shfl_xor(esum, 32);
    if (lane == 0) dpartA[rb*16 + hg] = esum;
  }
}

// ---- mergeA: grid 32 (b x 4 col-chunks), 256 thr -> qavB, wvecB ----
__global__ __launch_bounds__(256)
void k_mergeA(const float* __restrict__ cpartA, const float* __restrict__ dpartA,
              const float* __restrict__ wb,
              float* __restrict__ qavB, float* __restrict__ wvecB)
{
  __shared__ float dsum[16];
  const int blk = blockIdx.x, tid = threadIdx.x;
  const int b = blk >> 2, c = (blk & 3)*256 + tid;
  if (tid < 16){
    float d = 0.f;
    #pragma unroll
    for (int rb = 0; rb < 16; ++rb) d += dpartA[(b*16 + rb)*16 + tid];
    dsum[tid] = d;
  }
  __syncthreads();
  float s = 0.f;
  #pragma unroll
  for (int rb = 0; rb < 16; ++rb) s += cpartA[(size_t)(b*16 + rb)*1024 + c];
  const float qv = s / dsum[(c >> 6) & 15];
  qavB[b*1024 + c]  = qv;
  wvecB[b*1024 + c] = qv * wb[c & 63];
}

// ---- foldB: pBb[b,h,k](bf16) = sum_d Wk[k, h*64+d]*wvec[b,h,d]; csB = bk.wvec + bb ----
__global__ __launch_bounds__(256)
void k_foldB(const uint16_t* __restrict__ Wkt, const float* __restrict__ wvecB,
             const float* __restrict__ bk, const float* __restrict__ bbP,
             uint16_t* __restrict__ pBb, float* __restrict__ csB)
{
  __shared__ float wl[64];
  __shared__ float redc[64];
  const int bh = blockIdx.x, b = bh >> 4, h = bh & 15;
  const int tid = threadIdx.x;
  if (tid < 64) wl[tid] = wvecB[b*1024 + h*64 + tid];
  __syncthreads();
  const int k0 = tid*4;
  float a0 = 0.f, a1 = 0.f, a2 = 0.f, a3 = 0.f;
  for (int d = 0; d < 64; ++d){
    const float w = wl[d];
    const ushort4 r = *(const ushort4*)(Wkt + (size_t)(h*64 + d)*1024 + k0);
    a0 += bf2f(r.x)*w; a1 += bf2f(r.y)*w; a2 += bf2f(r.z)*w; a3 += bf2f(r.w)*w;
  }
  uint16_t* dst = pBb + (size_t)bh*1024 + k0;
  dst[0] = f2bf(a0); dst[1] = f2bf(a1); dst[2] = f2bf(a2); dst[3] = f2bf(a3);
  if (tid < 64) redc[tid] = bk[h*64 + tid] * wl[tid];
  __syncthreads();
  if (tid == 0){
    float s = 0.f;
    for (int i = 0; i < 64; ++i) s += redc[i];
    csB[bh] = s + bbP[0];
  }
}

// ---- scoreM: skinny MFMA GEMM, S = x @ pB^T -> EB = exp(S/8 + ...). ----
// grid 256 (64 rows each, 32 blocks/batch), 256 thr (4 waves x 16 rows).
// A-frag: x[row=l15][k=kk*32+l4*8+e]; B-frag: pBb[head=l15][same k] (n-major).
// D: col(l15)=head, row = l4*4+r  (verified k_newr pattern).
__global__ __launch_bounds__(256)
void k_scoreM(const uint16_t* __restrict__ xb, const uint16_t* __restrict__ pBb,
              const float* __restrict__ csB, const float* __restrict__ mask,
              float* __restrict__ EB, float* __restrict__ dpartB)
{
  __shared__ float sred[4][16];
  __shared__ float csl[16];
  const int blk = blockIdx.x, tid = threadIdx.x;
  const int b = blk >> 5;
  const int wave = tid >> 6, lane = tid & 63;
  const int l15 = lane & 15, l4 = lane >> 4;
  if (tid < 16) csl[tid] = csB[b*16 + tid];
  __syncthreads();
  const int row0 = blk*64 + wave*16;
  const uint16_t* pa = xb  + (size_t)(row0 + l15)*1024 + l4*8;
  const uint16_t* pb = pBb + (size_t)(b*16 + l15)*1024 + l4*8;

  f32x4 acc = {};
  #pragma unroll
  for (int kk = 0; kk < 32; ++kk){
    const bf16x8 af = *(const bf16x8*)(pa + kk*32);
    const bf16x8 bf = *(const bf16x8*)(pb + kk*32);
    acc = __builtin_amdgcn_mfma_f32_16x16x32_bf16(af, bf, acc, 0, 0, 0);
  }
  float es = 0.f;
  #pragma unroll
  for (int r = 0; r < 4; ++r){
    const int row = row0 + l4*4 + r;
    const float E = __expf((acc[r] + csl[l15])*0.125f + mask[row]);
    EB[(size_t)row*16 + l15] = E;
    es += E;
  }
  es += __shfl_xor(es, 16); es += __shfl_xor(es, 32);
  if (l4 == 0) sred[wave][l15] = es;
  __syncthreads();
  if (tid < 16)
    dpartB[blk*16 + tid] = sred[0][tid] + sred[1][tid] + sred[2][tid] + sred[3][tid];
}

// ---- xsumV: xwp[blk][h][col] = sum_{64 rows} EB[row][h]*x[row][col]. ----
// grid 256 (b = blk>>5), 256 thr: thread owns 4 cols x 16 head-accumulators.
__global__ __launch_bounds__(256)
void k_xsumV(const uint16_t* __restrict__ xb, const float* __restrict__ EB,
             float* __restrict__ xwp)
{
  const int blk = blockIdx.x, tid = threadIdx.x;
  const int row0 = blk*64;
  const int c0 = tid*4;
  float acc[16][4];
  #pragma unroll
  for (int h = 0; h < 16; ++h){
    #pragma unroll
    for (int c = 0; c < 4; ++c) acc[h][c] = 0.f;
  }
  for (int r = 0; r < 64; ++r){
    const int row = row0 + r;
    const ushort4 xv4 = *(const ushort4*)(xb + (size_t)row*1024 + c0);
    const float x0 = bf2f(xv4.x), x1 = bf2f(xv4.y), x2 = bf2f(xv4.z), x3 = bf2f(xv4.w);
    const float4* e4 = (const float4*)(EB + (size_t)row*16);
    const float4 e0 = e4[0], e1 = e4[1], e2 = e4[2], e3 = e4[3];
    #define ACCH(hh, ee) { acc[hh][0] += x0*(ee); acc[hh][1] += x1*(ee); \
                           acc[hh][2] += x2*(ee); acc[hh][3] += x3*(ee); }
    ACCH(0,  e0.x) ACCH(1,  e0.y) ACCH(2,  e0.z) ACCH(3,  e0.w)
    ACCH(4,  e1.x) ACCH(5,  e1.y) ACCH(6,  e1.z) ACCH(7,  e1.w)
    ACCH(8,  e2.x) ACCH(9,  e2.y) ACCH(10, e2.z) ACCH(11, e2.w)
    ACCH(12, e3.x) ACCH(13, e3.y) ACCH(14, e3.z) ACCH(15, e3.w)
    #undef ACCH
  }
  float* dst = xwp + (size_t)blk*16*1024;
  #pragma unroll
  for (int h = 0; h < 16; ++h)
    *(float4*)(dst + h*1024 + c0) =
        (float4){acc[h][0], acc[h][1], acc[h][2], acc[h][3]};
}

// ---- finalB: p_av = qav .* ((xwB@Wk_col)/denom + bk); WuPT = diag(p_av)@Wu ----
__global__ __launch_bounds__(512)
void k_finalB(const float* __restrict__ xwp, const float* __restrict__ dpartB,
              const float* __restrict__ qavB, const uint16_t* __restrict__ Wkt,
              const float* __restrict__ bk, const float* __restrict__ Wu,
              uint16_t* __restrict__ WuPT)
{
  __shared__ float xwl[1024];
  __shared__ float kvl[64];
  __shared__ float pavl[64];
  __shared__ float dsh;
  const int bh = blockIdx.x, b = bh >> 4, h = bh & 15;
  const int tid = threadIdx.x;
  #pragma unroll
  for (int i = 0; i < 2; ++i){
    const int idx = i*512 + tid;
    float s = 0.f;
    #pragma unroll
    for (int rc = 0; rc < 32; ++rc)
      s += xwp[((size_t)(b*32 + rc)*16 + h)*1024 + idx];
    xwl[idx] = s;
  }
  if (tid < 32){
    float d = dpartB[(b*32 + tid)*16 + h];
    d += __shfl_xor(d, 1); d += __shfl_xor(d, 2); d += __shfl_xor(d, 4);
    d += __shfl_xor(d, 8); d += __shfl_xor(d, 16);
    if (tid == 0) dsh = d;
  }
  __syncthreads();
  const int d = tid >> 3, q = tid & 7;
  const uint16_t* wrow = Wkt + (size_t)(h*64 + d)*1024 + q*128;
  const float* xwq = xwl + q*128;
  float s = 0.f;
  #pragma unroll
  for (int i = 0; i < 16; ++i){
    const bf16x8 v = *(const bf16x8*)(wrow + i*8);
    #pragma unroll
    for (int e = 0; e < 8; ++e) s += (float)v[e]*xwq[i*8+e];
  }
  s += __shfl_xor(s, 1); s += __shfl_xor(s, 2); s += __shfl_xor(s, 4);
  if (q == 0) kvl[d] = s;
  __syncthreads();
  if (tid < 64)
    pavl[tid] = qavB[b*1024 + h*64 + tid] * (kvl[tid]/dsh + bk[h*64 + tid]);
  __syncthreads();
  uint16_t* dst = WuPT + (size_t)bh*4096;
  for (int idx = tid; idx < 4096; idx += 512){
    const int i = idx & 63, jcol = idx >> 6;
    dst[idx] = f2bf(pavl[i]*Wu[i*64 + jcol]);
  }
}

// ---------------- newr = v @ WuP + bu + q   (per-head MFMA, qkv width 2048) --------
__global__ __launch_bounds__(256)
void k_newr(const uint16_t* __restrict__ qkv, const uint16_t* __restrict__ WuPT,
            const float* __restrict__ bu, uint16_t* __restrict__ newr)
{
  const int bh = blockIdx.x >> 3, st = blockIdx.x & 7;
  const int b = bh >> 4, h = bh & 15;
  const int tid = threadIdx.x, wave = tid >> 6, lane = tid & 63;
  const int l15 = lane & 15, l4 = lane >> 4;
  const int s0 = st*256 + wave*64;
  const uint16_t* vb = qkv + 1024 + h*64;
  const uint16_t* wt = WuPT + (size_t)bh*4096;

  f32x4 acc[4][4] = {};
  #pragma unroll
  for (int ks = 0; ks < 2; ++ks){
    bf16x8 bfr[4];
    #pragma unroll
    for (int n = 0; n < 4; ++n)
      bfr[n] = *(const bf16x8*)(wt + (n*16 + l15)*64 + ks*32 + l4*8);
    #pragma unroll
    for (int m = 0; m < 4; ++m){
      const int s = s0 + m*16 + l15;
      bf16x8 af = *(const bf16x8*)(vb + (size_t)(b*SS + s)*QKVW + ks*32 + l4*8);
      #pragma unroll
      for (int n = 0; n < 4; ++n)
        acc[m][n] = __builtin_amdgcn_mfma_f32_16x16x32_bf16(af, bfr[n], acc[m][n], 0, 0, 0);
    }
  }
  #pragma unroll
  for (int n = 0; n < 4; ++n){
    const int j = n*16 + l15;
    const float bj = bu[j];
    #pragma unroll
    for (int m = 0; m < 4; ++m){
      #pragma unroll
      for (int r = 0; r < 4; ++r){
        const int s = s0 + m*16 + l4*4 + r;
        const size_t qidx = (size_t)(b*SS + s)*QKVW + h*64 + j;
        const float q = bf2f(qkv[qidx]);
        newr[(size_t)(b*SS + s)*DD + h*64 + j] = f2bf(acc[m][n][r] + bj + q);
      }
    }
  }
}

// ---------------- layernorm (bf16 input h, f32 output) ----------------
__global__ __launch_bounds__(256)
void k_ln(const uint16_t* __restrict__ h16, const float* __restrict__ gamma,
          const float* __restrict__ beta, float* __restrict__ out)
{
  __shared__ float r1[256], r2[256];
  const int row = blockIdx.x, tid = threadIdx.x;
  const ushort4 hv = ((const ushort4*)(h16 + (size_t)row*DD))[tid];
  float v0 = bf2f(hv.x), v1 = bf2f(hv.y), v2 = bf2f(hv.z), v3 = bf2f(hv.w);
  float s  = v0 + v1 + v2 + v3;
  float ss = v0*v0 + v1*v1 + v2*v2 + v3*v3;
  r1[tid] = s; r2[tid] = ss; __syncthreads();
  for (int off = 128; off > 0; off >>= 1){
    if (tid < off){ r1[tid] += r1[tid+off]; r2[tid] += r2[tid+off]; }
    __syncthreads();
  }
  const float mu  = r1[0]*(1.f/1024.f);
  const float var = r2[0]*(1.f/1024.f) - mu*mu;
  const float inv = rsqrtf(var + 1e-6f);
  const float4 g  = ((const float4*)gamma)[tid];
  const float4 be = ((const float4*)beta)[tid];
  float4 o;
  o.x = (v0-mu)*inv*g.x + be.x;
  o.y = (v1-mu)*inv*g.y + be.y;
  o.z = (v2-mu)*inv*g.z + be.z;
  o.w = (v3-mu)*inv*g.w + be.w;
  ((float4*)(out + (size_t)row*DD))[tid] = o;
}

// ---------------- launch ----------------
extern "C" void kernel_launch(void* const* d_in, const int* in_sizes, int n_in,
                              void* d_out, int out_size, void* d_ws, size_t ws_size,
                              hipStream_t stream) {
  const float* x    = (const float*)d_in[0];
  const float* mask = (const float*)d_in[1];
  const float* Wq   = (const float*)d_in[2];
  const float* bq   = (const float*)d_in[3];
  const float* Wk   = (const float*)d_in[4];
  const float* bk   = (const float*)d_in[5];
  const float* Wv   = (const float*)d_in[6];
  const float* bv   = (const float*)d_in[7];
  const float* wa   = (const float*)d_in[8];
  const float* ba   = (const float*)d_in[9];
  const float* wb   = (const float*)d_in[10];
  const float* bb   = (const float*)d_in[11];
  const float* Wu   = (const float*)d_in[12];
  const float* bu   = (const float*)d_in[13];
  const float* Wo   = (const float*)d_in[14];
  const float* bo   = (const float*)d_in[15];
  const float* gamma= (const float*)d_in[16];
  const float* beta = (const float*)d_in[17];
  float* out = (float*)d_out;

  char* ws = (char*)d_ws;
  const size_t MB = 1ull << 20;
  uint16_t* xb    = (uint16_t*)(ws);              // 32 MB [16384][1024] bf16
  uint16_t* Wt    = (uint16_t*)(ws + 32*MB);      // 4 MB  [2048][1024]  bf16 (Wq^T;Wv^T)
  uint16_t* Wkt   = (uint16_t*)(ws + 36*MB);      // 2 MB  [1024][1024]  bf16 (Wk^T)
  uint16_t* WoT   = (uint16_t*)(ws + 38*MB);      // 2 MB  [1024][1024]  bf16
  float*    bqv   = (float*)   (ws + 40*MB);      // 8 KB  concat(bq,bv)
  uint16_t* WuPT  = (uint16_t*)(ws + 41*MB);      // 1 MB  [128][64][64] bf16
  uint16_t* qkv   = (uint16_t*)(ws + 42*MB);      // 64 MB [16384][2048] bf16 (q,v)
  uint16_t* hbuf16= (uint16_t*)(ws + 42*MB);      // 32 MB, aliases dead qkv after newr
  float* cpartA = (float*)(ws + 110*MB);          // 512KB [128][1024]
  float* dpartA = (float*)(ws + 111*MB);          // 8 KB  [128][16]
  float* qavB   = (float*)(ws + 112*MB);          // 32 KB [8][1024]
  float* wvecB  = (float*)(ws + 113*MB);          // 32 KB [8][1024]
  uint16_t* pBb = (uint16_t*)(ws + 114*MB);       // 256KB [8][16][1024] bf16
  float* csB    = (float*)(ws + 115*MB);          // 512 B [128]
  float* EB     = (float*)(ws + 116*MB);          // 1 MB  [16384][16]
  float* dpartB = (float*)(ws + 118*MB);          // 16 KB [256][16]
  float* xwp    = (float*)(ws + 119*MB);          // 16 MB [256][16][1024]
  uint16_t* newr= (uint16_t*)(ws + 138*MB);       // 32 MB [16384][1024] bf16

  k_prep<<<6156, 256, 0, stream>>>(x, Wq, Wk, Wv, Wo, bq, bv, xb, Wt, Wkt, WoT, bqv);

  k_gemm256<0,8><<<(MTOT/256)*(QKVW/256), 512, 0, stream>>>(
      xb, Wt, bqv, nullptr, qkv, wa, ba, mask, cpartA, dpartA);

  k_mergeA<<<32, 256, 0, stream>>>(cpartA, dpartA, wb, qavB, wvecB);
  k_foldB<<<128, 256, 0, stream>>>(Wkt, wvecB, bk, bb, pBb, csB);
  k_scoreM<<<256, 256, 0, stream>>>(xb, pBb, csB, mask, EB, dpartB);
  k_xsumV<<<256, 256, 0, stream>>>(xb, EB, xwp);
  k_finalB<<<128, 512, 0, stream>>>(xwp, dpartB, qavB, Wkt, bk, Wu, WuPT);

  k_newr<<<BB*HH*8, 256, 0, stream>>>(qkv, WuPT, bu, newr);
  k_gemm256<1,4><<<(MTOT/256)*(DD/256), 512, 0, stream>>>(
      newr, WoT, bo, xb, hbuf16, nullptr, nullptr, nullptr, nullptr, nullptr);
  k_ln<<<MTOT, 256, 0, stream>>>(hbuf16, gamma, beta, out);
}

// Round 13
// 216.488 us; speedup vs baseline: 1.2863x; 1.0220x over previous
//
#include <hip/hip_runtime.h>
#include <cstdint>

// ---------------- problem constants ----------------
#define BB 8
#define SS 2048
#define DD 1024
#define HH 16
#define HDIM 64
#define MTOT (BB*SS)          // 16384
#define QKVW 2048             // materialized columns: q (1024) + v (1024); k eliminated

typedef __attribute__((ext_vector_type(8))) __bf16 bf16x8;
typedef __attribute__((ext_vector_type(4))) float f32x4;

#define AS1(p) ((const __attribute__((address_space(1))) void*)(p))
#define AS3(p) ((__attribute__((address_space(3))) void*)(p))

__device__ __forceinline__ float bf2f(uint16_t u){
  return __uint_as_float(((uint32_t)u) << 16);
}
__device__ __forceinline__ uint16_t f2bf(float f){
  uint32_t u = __float_as_uint(f);
  return (uint16_t)((u + 0x7fffu + ((u >> 16) & 1u)) >> 16);
}

// ---------------- merged prep kernel ----------------
__global__ __launch_bounds__(256)
void k_prep(const float* __restrict__ x,
            const float* __restrict__ Wq, const float* __restrict__ Wk,
            const float* __restrict__ Wv, const float* __restrict__ Wo,
            const float* __restrict__ bq, const float* __restrict__ bv,
            uint16_t* __restrict__ xb, uint16_t* __restrict__ Wt,
            uint16_t* __restrict__ Wkt, uint16_t* __restrict__ WoT,
            float* __restrict__ bqv)
{
  __shared__ float t[32][33];
  const int blk = blockIdx.x, tid = threadIdx.x;
  if (blk < 2048){
    const int n4 = MTOT*DD/4;
    for (int i = blk*256 + tid; i < n4; i += 2048*256){
      float4 v = reinterpret_cast<const float4*>(x)[i];
      ushort4 o;
      o.x = f2bf(v.x); o.y = f2bf(v.y); o.z = f2bf(v.z); o.w = f2bf(v.w);
      reinterpret_cast<ushort4*>(xb)[i] = o;
    }
  } else if (blk < 6144){
    const int zb = blk - 2048;
    const int z = zb >> 10, rem = zb & 1023;
    const int by = rem >> 5, bx = rem & 31;
    const float* src = (z==0)?Wq:(z==1)?Wv:(z==2)?Wk:Wo;
    uint16_t* dst = (z==0)?Wt:(z==1)?(Wt + 1024*1024):(z==2)?Wkt:WoT;
    const int k0 = by*32, n0 = bx*32;
    const int tx = tid & 31, ty = tid >> 5;
    #pragma unroll
    for (int r = 0; r < 4; ++r)
      t[ty + r*8][tx] = src[(size_t)(k0 + ty + r*8)*1024 + n0 + tx];
    __syncthreads();
    #pragma unroll
    for (int r = 0; r < 4; ++r)
      dst[(size_t)(n0 + ty + r*8)*1024 + k0 + tx] = f2bf(t[tx][ty + r*8]);
  } else {
    const int i = (blk - 6144)*256 + tid;
    if (i < QKVW)
      bqv[i] = (i < 1024) ? bq[i] : bv[i-1024];
  }
}

// ============ 256x256 8-phase GEMM (R6 schedule) + fused alpha-pool epilogue ============
#define BARRIER __builtin_amdgcn_s_barrier()

#define READA(BUF, MH) { \
  const uint16_t* _sl = lds + ((BUF)*4 + (MH))*8192; \
  _Pragma("unroll") \
  for (int f = 0; f < 4; ++f) \
    _Pragma("unroll") \
    for (int ks = 0; ks < 2; ++ks) \
      a[f][ks] = *(const bf16x8*)(_sl + (wm*64 + f*16 + l15)*64 + (((ks*4 + l4) ^ l7)<<3)); \
}

#define READB(BUF, NH, BV) { \
  const uint16_t* _sl = lds + ((BUF)*4 + 2 + (NH))*8192; \
  _Pragma("unroll") \
  for (int j = 0; j < 2; ++j) \
    _Pragma("unroll") \
    for (int ks = 0; ks < 2; ++ks) \
      BV[j][ks] = *(const bf16x8*)(_sl + (wn*32 + j*16 + l15)*64 + (((ks*4 + l4) ^ l7)<<3)); \
}

#define MMA(MH, NH, BV) { \
  __builtin_amdgcn_s_setprio(1); \
  _Pragma("unroll") \
  for (int ks = 0; ks < 2; ++ks) \
    _Pragma("unroll") \
    for (int f = 0; f < 4; ++f) \
      _Pragma("unroll") \
      for (int j = 0; j < 2; ++j) \
        acc[(MH)*4+f][(NH)*2+j] = __builtin_amdgcn_mfma_f32_16x16x32_bf16(a[f][ks], BV[j][ks], acc[(MH)*4+f][(NH)*2+j], 0, 0, 0); \
  __builtin_amdgcn_s_setprio(0); }

#define STAGEA(T, H) { \
  char* _d = (char*)lds + ((((T)&1)*4 + (H))*16384) + wave*1024; \
  _Pragma("unroll") \
  for (int l = 0; l < 2; ++l) \
    __builtin_amdgcn_global_load_lds(AS1(pA + (l*131072 + (H)*65536 + (T)*64)), AS3(_d + l*8192), 16, 0, 0); \
}

#define STAGEB(T, H) { \
  char* _d = (char*)lds + ((((T)&1)*4 + 2 + (H))*16384) + wave*1024; \
  _Pragma("unroll") \
  for (int l = 0; l < 2; ++l) \
    __builtin_amdgcn_global_load_lds(AS1(pB + (l*131072 + (H)*32768 + (T)*64)), AS3(_d + l*8192), 16, 0, 0); \
}

template<int EPI, int NB_T>
__global__ __launch_bounds__(512)
void k_gemm256(const uint16_t* __restrict__ A, const uint16_t* __restrict__ Bt,
               const float* __restrict__ bias, const uint16_t* __restrict__ resid16,
               uint16_t* __restrict__ Cout,
               const float* __restrict__ waP, const float* __restrict__ baP,
               const float* __restrict__ maskP,
               float* __restrict__ cpartA, float* __restrict__ dpartA)
{
  constexpr int N = NB_T * 256;
  __shared__ uint16_t lds[8 * 8192];   // 128 KiB
  const int tid = threadIdx.x;
  const int lane = tid & 63, wave = tid >> 6;
  const int wm = wave >> 2, wn = wave & 3;
  const int l15 = lane & 15, l4 = lane >> 4, l7 = lane & 7;

  const int nwg = gridDim.x, cpx = nwg >> 3, bid = blockIdx.x;
  const int wg = (bid & 7) * cpx + (bid >> 3);
  const int m0 = (wg / NB_T) << 8, n0 = (wg % NB_T) << 8;

  const int colbase = (((tid & 7) ^ ((tid >> 3) & 7)) << 3);
  const uint16_t* pA = A  + (size_t)(m0 + (tid >> 3)) * 1024 + colbase;
  const uint16_t* pB = Bt + (size_t)(n0 + ((tid >> 8) << 6) + ((tid >> 3) & 31)) * 1024 + colbase;

  f32x4 acc[8][4] = {};
  bf16x8 a[4][2], b0[2][2], b1[2][2];

  STAGEA(0,0); STAGEB(0,1); STAGEA(0,1); STAGEB(0,0);
  STAGEA(1,0); STAGEB(1,1); STAGEA(1,1);
  asm volatile("s_waitcnt vmcnt(6)" ::: "memory");
  BARRIER;

  #pragma unroll
  for (int I = 0; I < 7; ++I){
    const int e = 2*I;
    READA(0,0); READB(0,0,b0); STAGEB(e+1, 0);
    BARRIER; MMA(0,0,b0); BARRIER;
    READB(0,1,b1); STAGEA(e+2, 0);
    BARRIER; MMA(0,1,b1); BARRIER;
    READA(0,1); STAGEB(e+2, 1);
    BARRIER; MMA(1,1,b1); BARRIER;
    STAGEA(e+2, 1);
    asm volatile("s_waitcnt vmcnt(6)" ::: "memory");
    BARRIER; MMA(1,0,b0); BARRIER;
    READA(1,0); READB(1,0,b0); STAGEB(e+2, 0);
    BARRIER; MMA(0,0,b0); BARRIER;
    READB(1,1,b1); STAGEA(e+3, 0);
    BARRIER; MMA(0,1,b1); BARRIER;
    READA(1,1); STAGEB(e+3, 1);
    BARRIER; MMA(1,1,b1); BARRIER;
    STAGEA(e+3, 1);
    asm volatile("s_waitcnt vmcnt(6)" ::: "memory");
    BARRIER; MMA(1,0,b0); BARRIER;
  }

  {
    READA(0,0); READB(0,0,b0); STAGEB(15, 0);
    BARRIER; MMA(0,0,b0); BARRIER;
    READB(0,1,b1);
    BARRIER; MMA(0,1,b1); BARRIER;
    READA(0,1);
    BARRIER; MMA(1,1,b1); BARRIER;
    asm volatile("s_waitcnt vmcnt(0)" ::: "memory");
    BARRIER; MMA(1,0,b0); BARRIER;
    READA(1,0); READB(1,0,b0);
    BARRIER; MMA(0,0,b0); BARRIER;
    READB(1,1,b1);
    BARRIER; MMA(0,1,b1); BARRIER;
    READA(1,1);
    BARRIER; MMA(1,1,b1); BARRIER;
    MMA(1,0,b0);
  }

  // ---- C-write
  #pragma unroll
  for (int mh = 0; mh < 2; ++mh)
  #pragma unroll
  for (int f = 0; f < 4; ++f)
  #pragma unroll
  for (int nh = 0; nh < 2; ++nh)
  #pragma unroll
  for (int j = 0; j < 2; ++j){
    const int gcol = n0 + wn*64 + nh*32 + j*16 + l15;
    const float bi = bias[gcol];
    const int rbase = m0 + wm*128 + mh*64 + f*16 + l4*4;
    #pragma unroll
    for (int rr = 0; rr < 4; ++rr){
      const size_t idx = (size_t)(rbase + rr)*N + gcol;
      float v = acc[mh*4+f][nh*2+j][rr] + bi;
      if (EPI == 1) v += bf2f(resid16[idx]);
      Cout[idx] = f2bf(v);
    }
  }

  // ---- fused alpha-pool over q columns (shift-free softmax, exact for small scores)
  if (EPI == 0 && n0 < 1024){
    const int hg = (n0 >> 6) + wn;
    const float bav = baP[0];
    float bcol[2][2], wv[2][2];
    #pragma unroll
    for (int nh = 0; nh < 2; ++nh)
    #pragma unroll
    for (int j = 0; j < 2; ++j){
      const int c = nh*32 + j*16 + l15;
      bcol[nh][j] = bias[n0 + wn*64 + c];
      wv[nh][j]   = waP[c];
    }
    float colacc[2][2] = {{0.f,0.f},{0.f,0.f}};
    float esum = 0.f;
    #pragma unroll
    for (int mh = 0; mh < 2; ++mh)
    #pragma unroll
    for (int f = 0; f < 4; ++f)
    #pragma unroll
    for (int rr = 0; rr < 4; ++rr){
      float qv[2][2];
      float p = 0.f;
      #pragma unroll
      for (int nh = 0; nh < 2; ++nh)
      #pragma unroll
      for (int j = 0; j < 2; ++j){
        qv[nh][j] = acc[mh*4+f][nh*2+j][rr] + bcol[nh][j];
        p += qv[nh][j] * wv[nh][j];
      }
      p += __shfl_xor(p, 1); p += __shfl_xor(p, 2);
      p += __shfl_xor(p, 4); p += __shfl_xor(p, 8);
      const int grow = m0 + wm*128 + mh*64 + f*16 + l4*4 + rr;
      const float E = __expf((p + bav)*0.125f + maskP[grow]);
      esum += E;
      #pragma unroll
      for (int nh = 0; nh < 2; ++nh)
      #pragma unroll
      for (int j = 0; j < 2; ++j)
        colacc[nh][j] += E * qv[nh][j];
    }
    const int rb = (m0 >> 7) + wm;
    #pragma unroll
    for (int nh = 0; nh < 2; ++nh)
    #pragma unroll
    for (int j = 0; j < 2; ++j){
      float v = colacc[nh][j];
      v += __shfl_xor(v, 16); v += __shfl_xor(v, 32);
      if (l4 == 0)
        cpartA[(size_t)rb*1024 + n0 + wn*64 + nh*32 + j*16 + l15] = v;
    }
    esum += __shfl_xor(esum, 16); esum += __shfl_xor(esum, 32);
    if (lane == 0) dpartA[rb*16 + hg] = esum;
  }
}

// ---- mergefold: (mergeA + foldB fused), grid 128 (bh), 256 thr ----
// qav[j] = col-sum/denom; wl = qav*wb; qavB out; pBb[b,h,k] = sum_d Wk[k,h*64+d]*wl[d];
// csB = bk.wl + bb.
__global__ __launch_bounds__(256)
void k_mergefold(const float* __restrict__ cpartA, const float* __restrict__ dpartA,
                 const float* __restrict__ wb, const uint16_t* __restrict__ Wkt,
                 const float* __restrict__ bk, const float* __restrict__ bbP,
                 float* __restrict__ qavB, uint16_t* __restrict__ pBb,
                 float* __restrict__ csB)
{
  __shared__ float wl[64];
  __shared__ float redc[64];
  const int bh = blockIdx.x, b = bh >> 4, h = bh & 15;
  const int tid = threadIdx.x;
  if (tid < 64){
    float s = 0.f;
    #pragma unroll
    for (int rb = 0; rb < 16; ++rb)
      s += cpartA[(size_t)(b*16 + rb)*1024 + h*64 + tid];
    float d = 0.f;
    #pragma unroll
    for (int rb = 0; rb < 16; ++rb)
      d += dpartA[(b*16 + rb)*16 + h];
    const float qv = s / d;
    qavB[b*1024 + h*64 + tid] = qv;
    wl[tid] = qv * wb[tid];
  }
  __syncthreads();
  const int k0 = tid*4;
  float a0 = 0.f, a1 = 0.f, a2 = 0.f, a3 = 0.f;
  for (int d2 = 0; d2 < 64; ++d2){
    const float w = wl[d2];
    const ushort4 r = *(const ushort4*)(Wkt + (size_t)(h*64 + d2)*1024 + k0);
    a0 += bf2f(r.x)*w; a1 += bf2f(r.y)*w; a2 += bf2f(r.z)*w; a3 += bf2f(r.w)*w;
  }
  uint16_t* dst = pBb + (size_t)bh*1024 + k0;
  dst[0] = f2bf(a0); dst[1] = f2bf(a1); dst[2] = f2bf(a2); dst[3] = f2bf(a3);
  if (tid < 64) redc[tid] = bk[h*64 + tid] * wl[tid];
  __syncthreads();
  if (tid == 0){
    float s = 0.f;
    for (int i = 0; i < 64; ++i) s += redc[i];
    csB[bh] = s + bbP[0];
  }
}

// ---- scoreXsum: fused MFMA beta-score + weighted x-sum. grid 256 (64 rows), 512 thr ----
// Phase 1 (waves 0-3): S = x @ pB^T via mfma (verified k_newr fragment pattern);
//   E = exp(S/8 + cs + mask) -> LDS el[64][16]; dpartB[blk][h] = sum E.
// Phase 2 (all 8 waves): thread owns 2 cols; acc[h] += el[r][h] * x[row][col]
//   (E broadcast from LDS, x re-read L2-hot); writes xwp[blk][h][1024].
__global__ __launch_bounds__(512)
void k_scoreXsum(const uint16_t* __restrict__ xb, const uint16_t* __restrict__ pBb,
                 const float* __restrict__ csB, const float* __restrict__ mask,
                 float* __restrict__ xwp, float* __restrict__ dpartB)
{
  __shared__ float el[64][16];
  __shared__ float sred[4][16];
  __shared__ float csl[16];
  const int blk = blockIdx.x, tid = threadIdx.x;
  const int b = blk >> 5;
  const int wave = tid >> 6, lane = tid & 63;
  const int l15 = lane & 15, l4 = lane >> 4;
  if (tid < 16) csl[tid] = csB[b*16 + tid];
  __syncthreads();
  const int row0 = blk*64;

  if (wave < 4){
    const int rw = row0 + wave*16;
    const uint16_t* pa = xb  + (size_t)(rw + l15)*1024 + l4*8;
    const uint16_t* pb = pBb + (size_t)(b*16 + l15)*1024 + l4*8;
    f32x4 acc = {};
    #pragma unroll
    for (int kk = 0; kk < 32; ++kk){
      const bf16x8 af = *(const bf16x8*)(pa + kk*32);
      const bf16x8 bf = *(const bf16x8*)(pb + kk*32);
      acc = __builtin_amdgcn_mfma_f32_16x16x32_bf16(af, bf, acc, 0, 0, 0);
    }
    float es = 0.f;
    #pragma unroll
    for (int r = 0; r < 4; ++r){
      const int rloc = wave*16 + l4*4 + r;
      const float E = __expf((acc[r] + csl[l15])*0.125f + mask[row0 + rloc]);
      el[rloc][l15] = E;
      es += E;
    }
    es += __shfl_xor(es, 16); es += __shfl_xor(es, 32);
    if (l4 == 0) sred[wave][l15] = es;
  }
  __syncthreads();
  if (tid < 16)
    dpartB[blk*16 + tid] = sred[0][tid] + sred[1][tid] + sred[2][tid] + sred[3][tid];

  // ---- phase 2: weighted x-sum over the same 64 rows
  const int c0 = tid*2;
  float acc0[16], acc1[16];
  #pragma unroll
  for (int h = 0; h < 16; ++h){ acc0[h] = 0.f; acc1[h] = 0.f; }
  for (int r = 0; r < 64; ++r){
    const uint32_t xv = *(const uint32_t*)(xb + (size_t)(row0 + r)*1024 + c0);
    const float x0 = __uint_as_float(xv << 16);
    const float x1 = __uint_as_float(xv & 0xffff0000u);
    const float4 e0 = *(const float4*)(&el[r][0]);
    const float4 e1 = *(const float4*)(&el[r][4]);
    const float4 e2 = *(const float4*)(&el[r][8]);
    const float4 e3 = *(const float4*)(&el[r][12]);
    acc0[0]  += x0*e0.x; acc1[0]  += x1*e0.x;
    acc0[1]  += x0*e0.y; acc1[1]  += x1*e0.y;
    acc0[2]  += x0*e0.z; acc1[2]  += x1*e0.z;
    acc0[3]  += x0*e0.w; acc1[3]  += x1*e0.w;
    acc0[4]  += x0*e1.x; acc1[4]  += x1*e1.x;
    acc0[5]  += x0*e1.y; acc1[5]  += x1*e1.y;
    acc0[6]  += x0*e1.z; acc1[6]  += x1*e1.z;
    acc0[7]  += x0*e1.w; acc1[7]  += x1*e1.w;
    acc0[8]  += x0*e2.x; acc1[8]  += x1*e2.x;
    acc0[9]  += x0*e2.y; acc1[9]  += x1*e2.y;
    acc0[10] += x0*e2.z; acc1[10] += x1*e2.z;
    acc0[11] += x0*e2.w; acc1[11] += x1*e2.w;
    acc0[12] += x0*e3.x; acc1[12] += x1*e3.x;
    acc0[13] += x0*e3.y; acc1[13] += x1*e3.y;
    acc0[14] += x0*e3.z; acc1[14] += x1*e3.z;
    acc0[15] += x0*e3.w; acc1[15] += x1*e3.w;
  }
  float* dst = xwp + (size_t)blk*16*1024;
  #pragma unroll
  for (int h = 0; h < 16; ++h)
    *(float2*)(dst + h*1024 + c0) = (float2){acc0[h], acc1[h]};
}

// ---- finalB: p_av = qav .* ((xwB@Wk_col)/denom + bk); WuPT = diag(p_av)@Wu ----
__global__ __launch_bounds__(512)
void k_finalB(const float* __restrict__ xwp, const float* __restrict__ dpartB,
              const float* __restrict__ qavB, const uint16_t* __restrict__ Wkt,
              const float* __restrict__ bk, const float* __restrict__ Wu,
              uint16_t* __restrict__ WuPT)
{
  __shared__ float xwl[1024];
  __shared__ float kvl[64];
  __shared__ float pavl[64];
  __shared__ float dsh;
  const int bh = blockIdx.x, b = bh >> 4, h = bh & 15;
  const int tid = threadIdx.x;
  #pragma unroll
  for (int i = 0; i < 2; ++i){
    const int idx = i*512 + tid;
    float s = 0.f;
    #pragma unroll
    for (int rc = 0; rc < 32; ++rc)
      s += xwp[((size_t)(b*32 + rc)*16 + h)*1024 + idx];
    xwl[idx] = s;
  }
  if (tid < 32){
    float d = dpartB[(b*32 + tid)*16 + h];
    d += __shfl_xor(d, 1); d += __shfl_xor(d, 2); d += __shfl_xor(d, 4);
    d += __shfl_xor(d, 8); d += __shfl_xor(d, 16);
    if (tid == 0) dsh = d;
  }
  __syncthreads();
  const int d = tid >> 3, q = tid & 7;
  const uint16_t* wrow = Wkt + (size_t)(h*64 + d)*1024 + q*128;
  const float* xwq = xwl + q*128;
  float s = 0.f;
  #pragma unroll
  for (int i = 0; i < 16; ++i){
    const bf16x8 v = *(const bf16x8*)(wrow + i*8);
    #pragma unroll
    for (int e = 0; e < 8; ++e) s += (float)v[e]*xwq[i*8+e];
  }
  s += __shfl_xor(s, 1); s += __shfl_xor(s, 2); s += __shfl_xor(s, 4);
  if (q == 0) kvl[d] = s;
  __syncthreads();
  if (tid < 64)
    pavl[tid] = qavB[b*1024 + h*64 + tid] * (kvl[tid]/dsh + bk[h*64 + tid]);
  __syncthreads();
  uint16_t* dst = WuPT + (size_t)bh*4096;
  for (int idx = tid; idx < 4096; idx += 512){
    const int i = idx & 63, jcol = idx >> 6;
    dst[idx] = f2bf(pavl[i]*Wu[i*64 + jcol]);
  }
}

// ---------------- newr = v @ WuP + bu + q   (per-head MFMA, qkv width 2048) --------
__global__ __launch_bounds__(256)
void k_newr(const uint16_t* __restrict__ qkv, const uint16_t* __restrict__ WuPT,
            const float* __restrict__ bu, uint16_t* __restrict__ newr)
{
  const int bh = blockIdx.x >> 3, st = blockIdx.x & 7;
  const int b = bh >> 4, h = bh & 15;
  const int tid = threadIdx.x, wave = tid >> 6, lane = tid & 63;
  const int l15 = lane & 15, l4 = lane >> 4;
  const int s0 = st*256 + wave*64;
  const uint16_t* vb = qkv + 1024 + h*64;
  const uint16_t* wt = WuPT + (size_t)bh*4096;

  f32x4 acc[4][4] = {};
  #pragma unroll
  for (int ks = 0; ks < 2; ++ks){
    bf16x8 bfr[4];
    #pragma unroll
    for (int n = 0; n < 4; ++n)
      bfr[n] = *(const bf16x8*)(wt + (n*16 + l15)*64 + ks*32 + l4*8);
    #pragma unroll
    for (int m = 0; m < 4; ++m){
      const int s = s0 + m*16 + l15;
      bf16x8 af = *(const bf16x8*)(vb + (size_t)(b*SS + s)*QKVW + ks*32 + l4*8);
      #pragma unroll
      for (int n = 0; n < 4; ++n)
        acc[m][n] = __builtin_amdgcn_mfma_f32_16x16x32_bf16(af, bfr[n], acc[m][n], 0, 0, 0);
    }
  }
  #pragma unroll
  for (int n = 0; n < 4; ++n){
    const int j = n*16 + l15;
    const float bj = bu[j];
    #pragma unroll
    for (int m = 0; m < 4; ++m){
      #pragma unroll
      for (int r = 0; r < 4; ++r){
        const int s = s0 + m*16 + l4*4 + r;
        const size_t qidx = (size_t)(b*SS + s)*QKVW + h*64 + j;
        const float q = bf2f(qkv[qidx]);
        newr[(size_t)(b*SS + s)*DD + h*64 + j] = f2bf(acc[m][n][r] + bj + q);
      }
    }
  }
}

// ---------------- layernorm (bf16 input h, f32 output) ----------------
__global__ __launch_bounds__(256)
void k_ln(const uint16_t* __restrict__ h16, const float* __restrict__ gamma,
          const float* __restrict__ beta, float* __restrict__ out)
{
  __shared__ float r1[256], r2[256];
  const int row = blockIdx.x, tid = threadIdx.x;
  const ushort4 hv = ((const ushort4*)(h16 + (size_t)row*DD))[tid];
  float v0 = bf2f(hv.x), v1 = bf2f(hv.y), v2 = bf2f(hv.z), v3 = bf2f(hv.w);
  float s  = v0 + v1 + v2 + v3;
  float ss = v0*v0 + v1*v1 + v2*v2 + v3*v3;
  r1[tid] = s; r2[tid] = ss; __syncthreads();
  for (int off = 128; off > 0; off >>= 1){
    if (tid < off){ r1[tid] += r1[tid+off]; r2[tid] += r2[tid+off]; }
    __syncthreads();
  }
  const float mu  = r1[0]*(1.f/1024.f);
  const float var = r2[0]*(1.f/1024.f) - mu*mu;
  const float inv = rsqrtf(var + 1e-6f);
  const float4 g  = ((const float4*)gamma)[tid];
  const float4 be = ((const float4*)beta)[tid];
  float4 o;
  o.x = (v0-mu)*inv*g.x + be.x;
  o.y = (v1-mu)*inv*g.y + be.y;
  o.z = (v2-mu)*inv*g.z + be.z;
  o.w = (v3-mu)*inv*g.w + be.w;
  ((float4*)(out + (size_t)row*DD))[tid] = o;
}

// ---------------- launch ----------------
extern "C" void kernel_launch(void* const* d_in, const int* in_sizes, int n_in,
                              void* d_out, int out_size, void* d_ws, size_t ws_size,
                              hipStream_t stream) {
  const float* x    = (const float*)d_in[0];
  const float* mask = (const float*)d_in[1];
  const float* Wq   = (const float*)d_in[2];
  const float* bq   = (const float*)d_in[3];
  const float* Wk   = (const float*)d_in[4];
  const float* bk   = (const float*)d_in[5];
  const float* Wv   = (const float*)d_in[6];
  const float* bv   = (const float*)d_in[7];
  const float* wa   = (const float*)d_in[8];
  const float* ba   = (const float*)d_in[9];
  const float* wb   = (const float*)d_in[10];
  const float* bb   = (const float*)d_in[11];
  const float* Wu   = (const float*)d_in[12];
  const float* bu   = (const float*)d_in[13];
  const float* Wo   = (const float*)d_in[14];
  const float* bo   = (const float*)d_in[15];
  const float* gamma= (const float*)d_in[16];
  const float* beta = (const float*)d_in[17];
  float* out = (float*)d_out;

  char* ws = (char*)d_ws;
  const size_t MB = 1ull << 20;
  uint16_t* xb    = (uint16_t*)(ws);              // 32 MB [16384][1024] bf16
  uint16_t* Wt    = (uint16_t*)(ws + 32*MB);      // 4 MB  [2048][1024]  bf16 (Wq^T;Wv^T)
  uint16_t* Wkt   = (uint16_t*)(ws + 36*MB);      // 2 MB  [1024][1024]  bf16 (Wk^T)
  uint16_t* WoT   = (uint16_t*)(ws + 38*MB);      // 2 MB  [1024][1024]  bf16
  float*    bqv   = (float*)   (ws + 40*MB);      // 8 KB  concat(bq,bv)
  uint16_t* WuPT  = (uint16_t*)(ws + 41*MB);      // 1 MB  [128][64][64] bf16
  uint16_t* qkv   = (uint16_t*)(ws + 42*MB);      // 64 MB [16384][2048] bf16 (q,v)
  uint16_t* hbuf16= (uint16_t*)(ws + 42*MB);      // 32 MB, aliases dead qkv after newr
  float* cpartA = (float*)(ws + 110*MB);          // 512KB [128][1024]
  float* dpartA = (float*)(ws + 111*MB);          // 8 KB  [128][16]
  float* qavB   = (float*)(ws + 112*MB);          // 32 KB [8][1024]
  uint16_t* pBb = (uint16_t*)(ws + 114*MB);       // 256KB [8][16][1024] bf16
  float* csB    = (float*)(ws + 115*MB);          // 512 B [128]
  float* dpartB = (float*)(ws + 118*MB);          // 16 KB [256][16]
  float* xwp    = (float*)(ws + 119*MB);          // 16 MB [256][16][1024]
  uint16_t* newr= (uint16_t*)(ws + 138*MB);       // 32 MB [16384][1024] bf16

  k_prep<<<6156, 256, 0, stream>>>(x, Wq, Wk, Wv, Wo, bq, bv, xb, Wt, Wkt, WoT, bqv);

  k_gemm256<0,8><<<(MTOT/256)*(QKVW/256), 512, 0, stream>>>(
      xb, Wt, bqv, nullptr, qkv, wa, ba, mask, cpartA, dpartA);

  k_mergefold<<<128, 256, 0, stream>>>(cpartA, dpartA, wb, Wkt, bk, bb, qavB, pBb, csB);
  k_scoreXsum<<<256, 512, 0, stream>>>(xb, pBb, csB, mask, xwp, dpartB);
  k_finalB<<<128, 512, 0, stream>>>(xwp, dpartB, qavB, Wkt, bk, Wu, WuPT);

  k_newr<<<BB*HH*8, 256, 0, stream>>>(qkv, WuPT, bu, newr);
  k_gemm256<1,4><<<(MTOT/256)*(DD/256), 512, 0, stream>>>(
      newr, WoT, bo, xb, hbuf16, nullptr, nullptr, nullptr, nullptr, nullptr);
  k_ln<<<MTOT, 256, 0, stream>>>(hbuf16, gamma, beta, out);
}